// Round 7
// baseline (1080.060 us; speedup 1.0000x reference)
//
#include <hip/hip_runtime.h>
#include <hip/hip_bf16.h>
#include <math.h>

#define N_NODES 50000
#define N_EDGES 640000
#define N_GRAPHS 2000
#define FN 64
#define FE 16
#define H 128
#define NL 2
#define DPW 4   // dsts per wave in edge kernel

typedef __attribute__((ext_vector_type(8))) short short8;
typedef __attribute__((ext_vector_type(4))) float float4v;
typedef __hip_bfloat16 bf16;

// ---------------- static workspace ----------------
static constexpr size_t AL = 256;
static constexpr size_t alup(size_t x) { return (x + AL - 1) & ~(AL - 1); }

static constexpr size_t SZ_HF    = (size_t)N_NODES * H * 4;
static constexpr size_t SZ_HB    = (size_t)N_NODES * H * 2;
static constexpr size_t SZ_XB    = (size_t)N_NODES * FN * 2;
static constexpr size_t SZ_PQMB  = (size_t)N_NODES * 384 * 2;
static constexpr size_t SZ_GH    = (size_t)N_NODES * 384 * 4;   // holds ghx bf16 (38.4MB used)
static constexpr size_t SZ_GI    = (size_t)N_NODES * 384 * 4;   // holds hW1 f32 (25.6MB used)
static constexpr size_t SZ_AGB   = (size_t)N_NODES * H * 2;
static constexpr size_t SZ_NF    = (size_t)N_NODES * 4;
static constexpr size_t SZ_WT    = (size_t)768 * 128 * 2;
static constexpr size_t SZ_WIHT  = (size_t)384 * 128 * 2;
static constexpr size_t SZ_EMBT  = (size_t)128 * 64 * 2;
static constexpr size_t SZ_BBIG  = (size_t)768 * 4;
static constexpr size_t SZ_G128  = (size_t)N_GRAPHS * 128 * 4;
static constexpr size_t SZ_G384  = (size_t)N_GRAPHS * 384 * 4;
static constexpr size_t SZ_GF    = (size_t)N_GRAPHS * 4;
static constexpr size_t SZ_CSE   = (size_t)N_EDGES * 8;

static constexpr size_t OFF_H0    = 0;
static constexpr size_t OFF_H1    = alup(OFF_H0 + SZ_HF);
static constexpr size_t OFF_H0B   = alup(OFF_H1 + SZ_HF);
static constexpr size_t OFF_H1B   = alup(OFF_H0B + SZ_HB);
static constexpr size_t OFF_XB    = alup(OFF_H1B + SZ_HB);
static constexpr size_t OFF_PQMB  = alup(OFF_XB + SZ_XB);
static constexpr size_t OFF_GH    = alup(OFF_PQMB + SZ_PQMB);
static constexpr size_t OFF_GI    = alup(OFF_GH + SZ_GH);
static constexpr size_t OFF_AGB   = alup(OFF_GI + SZ_GI);
static constexpr size_t OFF_ES    = alup(OFF_AGB + SZ_AGB);
static constexpr size_t OFF_WT    = alup(OFF_ES + SZ_NF);
static constexpr size_t OFF_WIHT  = alup(OFF_WT + SZ_WT);
static constexpr size_t OFF_EMBT  = alup(OFF_WIHT + SZ_WIHT);
static constexpr size_t OFF_BBIG  = alup(OFF_EMBT + SZ_EMBT);
static constexpr size_t OFF_G0    = alup(OFF_BBIG + SZ_BBIG);
static constexpr size_t OFF_GA    = alup(OFF_G0 + SZ_G128);
static constexpr size_t OFF_CTX   = alup(OFF_GA + SZ_G128);
static constexpr size_t OFF_GICTX = alup(OFF_CTX + SZ_G128);
static constexpr size_t OFF_GHB   = alup(OFF_GICTX + SZ_G384);
static constexpr size_t OFF_GSUM  = alup(OFF_GHB + SZ_G384);
static constexpr size_t OFF_DEG   = alup(OFF_GSUM + SZ_GF);
static constexpr size_t OFF_OFFS  = alup(OFF_DEG + SZ_NF);
static constexpr size_t OFF_CUR   = alup(OFF_OFFS + SZ_NF + 4);
static constexpr size_t OFF_CSE   = alup(OFF_CUR + SZ_NF);
static constexpr size_t OFF_GHIST = alup(OFF_CSE + SZ_CSE);
static constexpr size_t OFF_GOFFS = alup(OFF_GHIST + SZ_GF);
static constexpr size_t TOTAL_WS  = alup(OFF_GOFFS + SZ_GF + 4);

__device__ unsigned char g_afp_ws[TOTAL_WS];

__device__ inline float bf2f(unsigned short u) {
    unsigned int x = ((unsigned int)u) << 16;
    return __uint_as_float(x);
}

// ---------------- MFMA bf16 GEMM ----------------
// mode 0: C f32. mode bit0: relu. bit1: split768 -> Cb[r*384+c] (c<384), Cb2[r*384+c-384] (c>=384), both bf16.
// bit2: dual write (C f32 + Cb bf16, stride Ncol).
__global__ __launch_bounds__(256) void gemm_mfma(
    const bf16* __restrict__ Abf, const bf16* __restrict__ Btbf,
    const float* __restrict__ bias, float* __restrict__ C,
    bf16* __restrict__ Cb, bf16* __restrict__ Cb2,
    int M, int K, int Ncol, int mode)
{
    const unsigned short* A  = (const unsigned short*)Abf;
    const unsigned short* Bt = (const unsigned short*)Btbf;
    const int l  = threadIdx.x & 63;
    const int w  = threadIdx.x >> 6;
    const int wm = w >> 1, wn = w & 1;
    const int row0 = blockIdx.x * 64 + wm * 32;
    const int col0 = blockIdx.y * 64 + wn * 32;
    const int lr = l & 15;
    const int lk = (l >> 4) * 8;
    float4v acc[2][2] = {};
    for (int k0 = 0; k0 < K; k0 += 32) {
        short8 a[2], b[2];
        #pragma unroll
        for (int i = 0; i < 2; ++i) {
            int r = row0 + i * 16 + lr;
            if (r >= M) r = M - 1;
            a[i] = *(const short8*)(A + (size_t)r * K + k0 + lk);
        }
        #pragma unroll
        for (int j = 0; j < 2; ++j) {
            int c = col0 + j * 16 + lr;
            b[j] = *(const short8*)(Bt + (size_t)c * K + k0 + lk);
        }
        #pragma unroll
        for (int i = 0; i < 2; ++i)
            #pragma unroll
            for (int j = 0; j < 2; ++j)
                acc[i][j] = __builtin_amdgcn_mfma_f32_16x16x32_bf16(a[i], b[j], acc[i][j], 0, 0, 0);
    }
    const int orow = (l >> 4) * 4;
    const int ocol = l & 15;
    #pragma unroll
    for (int i = 0; i < 2; ++i) {
        #pragma unroll
        for (int j = 0; j < 2; ++j) {
            const int gc = col0 + j * 16 + ocol;
            const float bi = bias ? bias[gc] : 0.f;
            #pragma unroll
            for (int r = 0; r < 4; ++r) {
                const int gr = row0 + i * 16 + orow + r;
                if (gr >= M) continue;
                float v = acc[i][j][r] + bi;
                if (mode & 1) v = fmaxf(v, 0.f);
                if (mode & 2) {
                    if (gc < 384) Cb[(size_t)gr * 384 + gc] = __float2bfloat16(v);
                    else          Cb2[(size_t)gr * 384 + (gc - 384)] = __float2bfloat16(v);
                } else {
                    C[(size_t)gr * Ncol + gc] = v;
                    if (mode & 4) Cb[(size_t)gr * Ncol + gc] = __float2bfloat16(v);
                }
            }
        }
    }
}

// ---------------- fused gi-GEMM + GRU ----------------
// gi = aggr @ Wih^T + bih (never materialized); h' = GRU(gi, gh(bf16), h)
// block = 64 rows x 384 cols; wave w owns rows row0..row0+15, all 384 cols.
__global__ __launch_bounds__(256) void gemm_gru(
    const bf16* __restrict__ Abf, const bf16* __restrict__ Btbf,
    const float* __restrict__ bias, const bf16* __restrict__ ghb,
    const float* __restrict__ hold, float* __restrict__ hnew,
    bf16* __restrict__ hnewb, int M)
{
    const unsigned short* A  = (const unsigned short*)Abf;
    const unsigned short* Bt = (const unsigned short*)Btbf;
    const unsigned short* gh = (const unsigned short*)ghb;
    const int l  = threadIdx.x & 63;
    const int w  = threadIdx.x >> 6;
    const int row0 = blockIdx.x * 64 + w * 16;
    const int lr = l & 15;
    const int lk = (l >> 4) * 8;
    float4v acc[24] = {};
    for (int k0 = 0; k0 < 128; k0 += 32) {
        int r = row0 + lr;
        if (r >= M) r = M - 1;
        short8 a = *(const short8*)(A + (size_t)r * 128 + k0 + lk);
        #pragma unroll
        for (int j = 0; j < 24; ++j) {
            short8 b = *(const short8*)(Bt + (size_t)(j * 16 + lr) * 128 + k0 + lk);
            acc[j] = __builtin_amdgcn_mfma_f32_16x16x32_bf16(a, b, acc[j], 0, 0, 0);
        }
    }
    const int orow = (l >> 4) * 4;
    const int ocol = l & 15;
    #pragma unroll
    for (int a_ = 0; a_ < 8; ++a_) {
        const int c = a_ * 16 + ocol;
        const float bir = bias[c], biz = bias[c + 128], bin = bias[c + 256];
        #pragma unroll
        for (int r = 0; r < 4; ++r) {
            const int gr = row0 + orow + r;
            if (gr >= M) continue;
            float ir = acc[a_][r] + bir;
            float iz = acc[a_ + 8][r] + biz;
            float in = acc[a_ + 16][r] + bin;
            const unsigned short* ghp = gh + (size_t)gr * 384;
            float hr = bf2f(ghp[c]);
            float hz = bf2f(ghp[128 + c]);
            float hn = bf2f(ghp[256 + c]);
            float rg = 1.f / (1.f + __expf(-(ir + hr)));
            float zg = 1.f / (1.f + __expf(-(iz + hz)));
            float ng = tanhf(in + rg * hn);
            float hv = hold[(size_t)gr * 128 + c];
            float o = (1.f - zg) * ng + zg * hv;
            hnew[(size_t)gr * 128 + c] = o;
            hnewb[(size_t)gr * 128 + c] = __float2bfloat16(o);
        }
    }
}

// ---------------- f32 GEMM (small readout matmuls only) ----------------
#define GBM 64
#define GBN 64
#define GBK 32
__global__ __launch_bounds__(256) void gemm_f32(
    const float* __restrict__ A, const float* __restrict__ B,
    const float* __restrict__ bias, float* __restrict__ C,
    int M, int K, int Ncol)
{
    __shared__ float As[GBK][GBM + 4];
    __shared__ float Bs[GBK][GBN + 4];
    const int tx = threadIdx.x & 15;
    const int ty = threadIdx.x >> 4;
    const int row0 = blockIdx.x * GBM;
    const int col0 = blockIdx.y * GBN;
    float acc[4][4] = {};
    for (int k0 = 0; k0 < K; k0 += GBK) {
        for (int i = threadIdx.x; i < GBM * GBK; i += 256) {
            int r = i / GBK, c = i % GBK;
            float v = 0.f;
            if (row0 + r < M) v = A[(size_t)(row0 + r) * K + k0 + c];
            As[c][r] = v;
        }
        for (int i = threadIdx.x; i < GBK * GBN; i += 256) {
            int r = i / GBN, c = i % GBN;
            float v = 0.f;
            if (col0 + c < Ncol) v = B[(size_t)(k0 + r) * Ncol + col0 + c];
            Bs[r][c] = v;
        }
        __syncthreads();
        #pragma unroll
        for (int k = 0; k < GBK; ++k) {
            float a[4], b[4];
            #pragma unroll
            for (int i = 0; i < 4; ++i) a[i] = As[k][ty * 4 + i];
            #pragma unroll
            for (int j = 0; j < 4; ++j) b[j] = Bs[k][tx * 4 + j];
            #pragma unroll
            for (int i = 0; i < 4; ++i)
                #pragma unroll
                for (int j = 0; j < 4; ++j)
                    acc[i][j] = fmaf(a[i], b[j], acc[i][j]);
        }
        __syncthreads();
    }
    #pragma unroll
    for (int i = 0; i < 4; ++i) {
        int r = row0 + ty * 4 + i;
        if (r >= M) continue;
        #pragma unroll
        for (int j = 0; j < 4; ++j) {
            int c = col0 + tx * 4 + j;
            if (c >= Ncol) continue;
            C[(size_t)r * Ncol + c] = acc[i][j] + (bias ? bias[c] : 0.f);
        }
    }
}

// ---------------- weight packing ----------------
__global__ void pack_weights_bt(const float* __restrict__ attW1,
                                const float* __restrict__ mlpW,
                                const float* __restrict__ whh,
                                const float* __restrict__ attb1,
                                const float* __restrict__ mlpb,
                                const float* __restrict__ bhh,
                                bf16* __restrict__ wt, float* __restrict__ bbig)
{
    int idx = blockIdx.x * blockDim.x + threadIdx.x;
    if (idx >= 768 * 128) return;
    int j = idx >> 7, k = idx & 127;
    float v;
    if (j < 128)      v = attW1[k * 128 + j];
    else if (j < 256) v = attW1[(128 + k) * 128 + (j - 128)];
    else if (j < 384) v = mlpW[k * 128 + (j - 256)];
    else              v = whh[k * 384 + (j - 384)];
    wt[idx] = __float2bfloat16(v);
    if (k == 0) {
        float b;
        if (j < 128)      b = attb1[j];
        else if (j < 256) b = 0.f;
        else if (j < 384) b = mlpb[j - 256];
        else              b = bhh[j - 384];
        bbig[j] = b;
    }
}

__global__ void transpose_cast(const float* __restrict__ in, bf16* __restrict__ out,
                               int K, int Ncol)
{
    int idx = blockIdx.x * blockDim.x + threadIdx.x;
    if (idx >= K * Ncol) return;
    int k = idx / Ncol, j = idx % Ncol;
    out[(size_t)j * K + k] = __float2bfloat16(in[idx]);
}

__global__ void cast_bf16_kernel(const float* __restrict__ in, bf16* __restrict__ out, int n)
{
    int idx = blockIdx.x * blockDim.x + threadIdx.x;
    if (idx < n) out[idx] = __float2bfloat16(in[idx]);
}

// ---------------- CSR build ----------------
__global__ void hist_dst_kernel(const int* __restrict__ ei, int* __restrict__ deg) {
    int e = blockIdx.x * blockDim.x + threadIdx.x;
    if (e < N_EDGES) atomicAdd(&deg[ei[N_EDGES + e]], 1);
}
__global__ void hist_batch_kernel(const int* __restrict__ batch, int* __restrict__ hist) {
    int n = blockIdx.x * blockDim.x + threadIdx.x;
    if (n < N_NODES) atomicAdd(&hist[batch[n]], 1);
}
__global__ __launch_bounds__(1024) void scan_excl_kernel(
    const int* __restrict__ in, int* __restrict__ out, int n)
{
    __shared__ int buf[1024];
    __shared__ int carry_s;
    if (threadIdx.x == 0) carry_s = 0;
    __syncthreads();
    for (int base = 0; base < n; base += 1024) {
        int i = base + threadIdx.x;
        int v = (i < n) ? in[i] : 0;
        __syncthreads();
        buf[threadIdx.x] = v;
        __syncthreads();
        for (int off = 1; off < 1024; off <<= 1) {
            int t = 0;
            if (threadIdx.x >= off) t = buf[threadIdx.x - off];
            __syncthreads();
            buf[threadIdx.x] += t;
            __syncthreads();
        }
        int carry = carry_s;
        __syncthreads();
        if (threadIdx.x == 0) carry_s = carry + buf[1023];
        if (i < n) out[i] = carry + buf[threadIdx.x] - v;
    }
    __syncthreads();
    if (threadIdx.x == 0) out[n] = carry_s;
}
__global__ void scatter_cse_kernel(const int* __restrict__ ei, const int* __restrict__ offs,
                                   int* __restrict__ cur, int2* __restrict__ cse) {
    int e = blockIdx.x * blockDim.x + threadIdx.x;
    if (e >= N_EDGES) return;
    int d = ei[N_EDGES + e];
    int pos = offs[d] + atomicAdd(&cur[d], 1);
    cse[pos] = make_int2(ei[e], e);
}

// ---------------- fused edge attention + aggregation ----------------
// wave per DPW consecutive dsts; 2-edge-deep software pipeline (slots A/B).
__global__ __launch_bounds__(256) void edge_fused_kernel(
    const bf16* __restrict__ pqm_b,
    const int2* __restrict__ cse, const float* __restrict__ ea,
    const float* __restrict__ w1c_g, const float* __restrict__ w2_g,
    const float* __restrict__ b2_g, const float* __restrict__ mlpw2_g,
    const int* __restrict__ offs, bf16* __restrict__ aggrb)
{
    const unsigned short* pqm = (const unsigned short*)pqm_b;
    const int wv = threadIdx.x >> 6, lane = threadIdx.x & 63;
    const int c0 = lane * 2;
    float w1r[16][2], wmr[16][2];
    #pragma unroll
    for (int k = 0; k < 16; ++k) {
        w1r[k][0] = w1c_g[k * 128 + c0];
        w1r[k][1] = w1c_g[k * 128 + c0 + 1];
        wmr[k][0] = mlpw2_g[k * 128 + c0];
        wmr[k][1] = mlpw2_g[k * 128 + c0 + 1];
    }
    const float w20 = w2_g[c0], w21 = w2_g[c0 + 1];
    const float b2 = b2_g[0];
    const int dbase = __builtin_amdgcn_readfirstlane((blockIdx.x * 4 + wv) * DPW);

    for (int rep = 0; rep < DPW; ++rep) {
        const int d = dbase + rep;
        if (d >= N_NODES) break;
        const ushort2 pu = *(const ushort2*)(pqm + (size_t)d * 384 + c0);
        const float p0 = bf2f(pu.x), p1 = bf2f(pu.y);
        float acc0 = 0.f, acc1 = 0.f, ssum = 0.f;
        const int b = offs[d], en = offs[d + 1];

        auto compute = [&](float t0, float t1, float m0, float m1, const float* er) {
            #pragma unroll
            for (int k = 0; k < 16; ++k) {
                t0 = fmaf(er[k], w1r[k][0], t0);
                t1 = fmaf(er[k], w1r[k][1], t1);
                m0 = fmaf(er[k], wmr[k][0], m0);
                m1 = fmaf(er[k], wmr[k][1], m1);
            }
            float a0 = (t0 > 0.f) ? t0 : 0.2f * t0;
            float a1 = (t1 > 0.f) ? t1 : 0.2f * t1;
            float sp = a0 * w20 + a1 * w21;
            #pragma unroll
            for (int off = 32; off; off >>= 1) sp += __shfl_xor(sp, off);
            const float ex = __expf(sp + b2);
            ssum += ex;
            acc0 = fmaf(ex, fmaxf(m0, 0.f), acc0);
            acc1 = fmaf(ex, fmaxf(m1, 0.f), acc1);
        };

        if (b < en) {
            // prefetch slot A (edge b), slot B (edge b+1)
            int2 seA = cse[b];
            const unsigned short* psA = pqm + (size_t)seA.x * 384;
            ushort2 quA = *(const ushort2*)(psA + 128 + c0);
            ushort2 muA = *(const ushort2*)(psA + 256 + c0);
            const float4* eapA = (const float4*)(ea + (size_t)seA.y * 16);
            float4 eA0 = eapA[0], eA1 = eapA[1], eA2 = eapA[2], eA3 = eapA[3];
            ushort2 quB, muB; float4 eB0, eB1, eB2, eB3;
            if (b + 1 < en) {
                int2 seB = cse[b + 1];
                const unsigned short* psB = pqm + (size_t)seB.x * 384;
                quB = *(const ushort2*)(psB + 128 + c0);
                muB = *(const ushort2*)(psB + 256 + c0);
                const float4* eapB = (const float4*)(ea + (size_t)seB.y * 16);
                eB0 = eapB[0]; eB1 = eapB[1]; eB2 = eapB[2]; eB3 = eapB[3];
            }
            int i = b;
            for (; i + 1 < en; i += 2) {
                // --- edge i from slot A; refill A with edge i+2
                {
                    float t0 = p0 + bf2f(quA.x), t1 = p1 + bf2f(quA.y);
                    float m0 = bf2f(muA.x), m1 = bf2f(muA.y);
                    float er[16];
                    er[0]=eA0.x; er[1]=eA0.y; er[2]=eA0.z; er[3]=eA0.w;
                    er[4]=eA1.x; er[5]=eA1.y; er[6]=eA1.z; er[7]=eA1.w;
                    er[8]=eA2.x; er[9]=eA2.y; er[10]=eA2.z; er[11]=eA2.w;
                    er[12]=eA3.x; er[13]=eA3.y; er[14]=eA3.z; er[15]=eA3.w;
                    if (i + 2 < en) {
                        int2 se = cse[i + 2];
                        const unsigned short* ps = pqm + (size_t)se.x * 384;
                        quA = *(const ushort2*)(ps + 128 + c0);
                        muA = *(const ushort2*)(ps + 256 + c0);
                        const float4* eap = (const float4*)(ea + (size_t)se.y * 16);
                        eA0 = eap[0]; eA1 = eap[1]; eA2 = eap[2]; eA3 = eap[3];
                    }
                    compute(t0, t1, m0, m1, er);
                }
                // --- edge i+1 from slot B; refill B with edge i+3
                {
                    float t0 = p0 + bf2f(quB.x), t1 = p1 + bf2f(quB.y);
                    float m0 = bf2f(muB.x), m1 = bf2f(muB.y);
                    float er[16];
                    er[0]=eB0.x; er[1]=eB0.y; er[2]=eB0.z; er[3]=eB0.w;
                    er[4]=eB1.x; er[5]=eB1.y; er[6]=eB1.z; er[7]=eB1.w;
                    er[8]=eB2.x; er[9]=eB2.y; er[10]=eB2.z; er[11]=eB2.w;
                    er[12]=eB3.x; er[13]=eB3.y; er[14]=eB3.z; er[15]=eB3.w;
                    if (i + 3 < en) {
                        int2 se = cse[i + 3];
                        const unsigned short* ps = pqm + (size_t)se.x * 384;
                        quB = *(const ushort2*)(ps + 128 + c0);
                        muB = *(const ushort2*)(ps + 256 + c0);
                        const float4* eap = (const float4*)(ea + (size_t)se.y * 16);
                        eB0 = eap[0]; eB1 = eap[1]; eB2 = eap[2]; eB3 = eap[3];
                    }
                    compute(t0, t1, m0, m1, er);
                }
            }
            if (i < en) { // odd tail: slot A holds edge i
                float t0 = p0 + bf2f(quA.x), t1 = p1 + bf2f(quA.y);
                float m0 = bf2f(muA.x), m1 = bf2f(muA.y);
                float er[16];
                er[0]=eA0.x; er[1]=eA0.y; er[2]=eA0.z; er[3]=eA0.w;
                er[4]=eA1.x; er[5]=eA1.y; er[6]=eA1.z; er[7]=eA1.w;
                er[8]=eA2.x; er[9]=eA2.y; er[10]=eA2.z; er[11]=eA2.w;
                er[12]=eA3.x; er[13]=eA3.y; er[14]=eA3.z; er[15]=eA3.w;
                compute(t0, t1, m0, m1, er);
            }
        }
        const float inv = 1.f / (ssum + 1e-16f);
        bf16* outp = aggrb + (size_t)d * 128 + c0;
        outp[0] = __float2bfloat16(acc0 * inv);
        outp[1] = __float2bfloat16(acc1 * inv);
    }
}

// ---------------- GRU elementwise (readout graph GRU only) ----------------
__global__ void gru_elem_kernel(const float* __restrict__ gi,
                                const float* __restrict__ gh,
                                const float* __restrict__ hold, float* __restrict__ hnew,
                                int rows)
{
    int idx = blockIdx.x * blockDim.x + threadIdx.x;
    if (idx >= rows * H) return;
    int r = idx >> 7, c = idx & 127;
    float ir = gi[(size_t)r * 384 + c];
    float iz = gi[(size_t)r * 384 + 128 + c];
    float in = gi[(size_t)r * 384 + 256 + c];
    float hr = gh[(size_t)r * 384 + c];
    float hz = gh[(size_t)r * 384 + 128 + c];
    float hn = gh[(size_t)r * 384 + 256 + c];
    float rg = 1.f / (1.f + __expf(-(ir + hr)));
    float zg = 1.f / (1.f + __expf(-(iz + hz)));
    float ng = tanhf(in + rg * hn);
    float hv = hold[idx];
    hnew[idx] = (1.f - zg) * ng + zg * hv;
}

// ---------------- graph pooling / readout ----------------
__global__ __launch_bounds__(128) void graph_pool_sum(
    const float* __restrict__ h, const int* __restrict__ goffs, float* __restrict__ g0)
{
    int g = blockIdx.x, c = threadIdx.x;
    int b = goffs[g], e2 = goffs[g + 1];
    float acc = 0.f;
    for (int i = b; i < e2; ++i) acc += h[(size_t)i * 128 + c];
    g0[(size_t)g * 128 + c] = acc;
}

// s = tanh(hW1[n,:]) . W2 ; es = exp(s + b2); gsum[batch] += es   (hW1 includes b1)
__global__ __launch_bounds__(256) void node_score2_kernel(
    const float* __restrict__ hW1, const float* __restrict__ W2,
    const float* __restrict__ b2, const int* __restrict__ batch,
    float* __restrict__ es, float* __restrict__ gsum)
{
    const int wv = threadIdx.x >> 6, lane = threadIdx.x & 63;
    const int n = blockIdx.x * 4 + wv;
    if (n >= N_NODES) return;
    const int c0 = lane * 2;
    float sp = tanhf(hW1[(size_t)n * 128 + c0]) * W2[c0]
             + tanhf(hW1[(size_t)n * 128 + c0 + 1]) * W2[c0 + 1];
    #pragma unroll
    for (int off = 32; off; off >>= 1) sp += __shfl_xor(sp, off);
    if (lane == 0) {
        float ex = __expf(sp + b2[0]);
        es[n] = ex;
        atomicAdd(&gsum[batch[n]], ex);
    }
}

__global__ __launch_bounds__(128) void graph_ctx_kernel(
    const float* __restrict__ h, const int* __restrict__ goffs,
    const float* __restrict__ es, const float* __restrict__ gsum,
    float* __restrict__ ctx)
{
    int g = blockIdx.x, c = threadIdx.x;
    float invs = 1.f / (gsum[g] + 1e-16f);
    int b = goffs[g], e2 = goffs[g + 1];
    float acc = 0.f;
    for (int i = b; i < e2; ++i) acc = fmaf(es[i] * invs, h[(size_t)i * 128 + c], acc);
    ctx[(size_t)g * 128 + c] = acc;
}

extern "C" void kernel_launch(void* const* d_in, const int* in_sizes, int n_in,
                              void* d_out, int out_size, void* d_ws, size_t ws_size,
                              hipStream_t stream) {
    const float* x      = (const float*)d_in[0];
    const int*   ei     = (const int*)d_in[1];
    const float* ea     = (const float*)d_in[2];
    const int*   batch  = (const int*)d_in[3];
    const float* embW   = (const float*)d_in[4];
    const float* embB   = (const float*)d_in[5];
    const float* attW1  = (const float*)d_in[6];
    const float* attb1  = (const float*)d_in[7];
    const float* attW2  = (const float*)d_in[8];
    const float* attb2  = (const float*)d_in[9];
    const float* mlpW   = (const float*)d_in[10];
    const float* mlpb   = (const float*)d_in[11];
    const float* gWih   = (const float*)d_in[12];
    const float* gWhh   = (const float*)d_in[13];
    const float* gbih   = (const float*)d_in[14];
    const float* gbhh   = (const float*)d_in[15];
    const float* gattW1 = (const float*)d_in[16];
    const float* gattb1 = (const float*)d_in[17];
    const float* gattW2 = (const float*)d_in[18];
    const float* gattb2 = (const float*)d_in[19];
    const float* ggWih  = (const float*)d_in[20];
    const float* ggWhh  = (const float*)d_in[21];
    const float* ggbih  = (const float*)d_in[22];
    const float* ggbhh  = (const float*)d_in[23];
    float* out = (float*)d_out;

    void* basep = nullptr;
    (void)hipGetSymbolAddress(&basep, HIP_SYMBOL(g_afp_ws));
    char* base = (char*)basep;
    float* h0    = (float*)(base + OFF_H0);
    float* h1    = (float*)(base + OFF_H1);
    bf16*  h0b   = (bf16*)(base + OFF_H0B);
    bf16*  h1b   = (bf16*)(base + OFF_H1B);
    bf16*  xb    = (bf16*)(base + OFF_XB);
    bf16*  pqmb  = (bf16*)(base + OFF_PQMB);
    bf16*  ghx   = (bf16*)(base + OFF_GH);     // node gh, bf16 [N,384]
    float* hW1   = (float*)(base + OFF_GI);    // readout scratch f32 [N,128]
    bf16*  aggrb = (bf16*)(base + OFF_AGB);
    float* es    = (float*)(base + OFF_ES);
    bf16*  wt    = (bf16*)(base + OFF_WT);
    bf16*  wiht  = (bf16*)(base + OFF_WIHT);
    bf16*  embt  = (bf16*)(base + OFF_EMBT);
    float* bbig  = (float*)(base + OFF_BBIG);
    float* g0b   = (float*)(base + OFF_G0);
    float* gAb   = (float*)(base + OFF_GA);
    float* ctx   = (float*)(base + OFF_CTX);
    float* gictx = (float*)(base + OFF_GICTX);
    float* ghr   = (float*)(base + OFF_GHB);   // readout graph gh f32 [G,384]
    float* gsum  = (float*)(base + OFF_GSUM);
    int*   deg   = (int*)(base + OFF_DEG);
    int*   offs  = (int*)(base + OFF_OFFS);
    int*   cur   = (int*)(base + OFF_CUR);
    int2*  cse   = (int2*)(base + OFF_CSE);
    int*   ghist = (int*)(base + OFF_GHIST);
    int*   goffs = (int*)(base + OFF_GOFFS);

    (void)hipMemsetAsync(deg, 0, SZ_NF, stream);
    (void)hipMemsetAsync(cur, 0, SZ_NF, stream);
    (void)hipMemsetAsync(ghist, 0, SZ_GF, stream);
    (void)hipMemsetAsync(gsum, 0, SZ_GF, stream);

    hist_dst_kernel<<<(N_EDGES + 255) / 256, 256, 0, stream>>>(ei, deg);
    scan_excl_kernel<<<1, 1024, 0, stream>>>(deg, offs, N_NODES);
    scatter_cse_kernel<<<(N_EDGES + 255) / 256, 256, 0, stream>>>(ei, offs, cur, cse);
    hist_batch_kernel<<<(N_NODES + 255) / 256, 256, 0, stream>>>(batch, ghist);
    scan_excl_kernel<<<1, 1024, 0, stream>>>(ghist, goffs, N_GRAPHS);

    cast_bf16_kernel<<<(N_NODES * FN + 255) / 256, 256, 0, stream>>>(x, xb, N_NODES * FN);
    transpose_cast<<<(FN * 128 + 255) / 256, 256, 0, stream>>>(embW, embt, FN, 128);

    {
        dim3 g((N_NODES + 63) / 64, 128 / 64);
        gemm_mfma<<<g, 256, 0, stream>>>(xb, embt, embB, h0, h0b, nullptr,
                                         N_NODES, FN, 128, 1 | 4);
    }

    float* hcur = h0;  bf16* hcurb = h0b;
    float* hnext = h1; bf16* hnextb = h1b;
    for (int l = 0; l < NL; ++l) {
        pack_weights_bt<<<(768 * 128 + 255) / 256, 256, 0, stream>>>(
            attW1 + (size_t)l * 272 * 128, mlpW + (size_t)l * 144 * 128,
            gWhh + (size_t)l * 128 * 384, attb1 + l * 128, mlpb + l * 128,
            gbhh + l * 384, wt, bbig);
        {
            dim3 g((N_NODES + 63) / 64, 768 / 64);
            gemm_mfma<<<g, 256, 0, stream>>>(hcurb, wt, bbig, nullptr, pqmb, ghx,
                                             N_NODES, 128, 768, 2);
        }
        edge_fused_kernel<<<(N_NODES + 4 * DPW - 1) / (4 * DPW), 256, 0, stream>>>(
            pqmb, cse, ea, attW1 + (size_t)l * 272 * 128 + 256 * 128,
            attW2 + (size_t)l * 128, attb2 + l,
            mlpW + (size_t)l * 144 * 128 + 128 * 128,
            offs, aggrb);
        transpose_cast<<<(128 * 384 + 255) / 256, 256, 0, stream>>>(
            gWih + (size_t)l * 128 * 384, wiht, 128, 384);
        gemm_gru<<<(N_NODES + 63) / 64, 256, 0, stream>>>(
            aggrb, wiht, gbih + l * 384, ghx, hcur, hnext, hnextb, N_NODES);
        float* t = hcur; hcur = hnext; hnext = t;
        bf16* tb = hcurb; hcurb = hnextb; hnextb = tb;
    }

    // readout (h fixed across T -> ctx computed once)
    graph_pool_sum<<<N_GRAPHS, 128, 0, stream>>>(hcur, goffs, g0b);
    transpose_cast<<<(128 * 128 + 255) / 256, 256, 0, stream>>>(gattW1, wiht, 128, 128);
    {
        dim3 g((N_NODES + 63) / 64, 128 / 64);
        gemm_mfma<<<g, 256, 0, stream>>>(hcurb, wiht, gattb1, hW1, nullptr, nullptr,
                                         N_NODES, 128, 128, 0);
    }
    node_score2_kernel<<<(N_NODES + 3) / 4, 256, 0, stream>>>(
        hW1, gattW2, gattb2, batch, es, gsum);
    graph_ctx_kernel<<<N_GRAPHS, 128, 0, stream>>>(hcur, goffs, es, gsum, ctx);

    dim3 gg((N_GRAPHS + 63) / 64, 384 / 64);
    gemm_f32<<<gg, 256, 0, stream>>>(ctx, ggWih, ggbih, gictx, N_GRAPHS, H, 384);
    gemm_f32<<<gg, 256, 0, stream>>>(g0b, ggWhh, ggbhh, ghr, N_GRAPHS, H, 384);
    gru_elem_kernel<<<((size_t)N_GRAPHS * H + 255) / 256, 256, 0, stream>>>(
        gictx, ghr, g0b, gAb, N_GRAPHS);
    gemm_f32<<<gg, 256, 0, stream>>>(gAb, ggWhh, ggbhh, ghr, N_GRAPHS, H, 384);
    gru_elem_kernel<<<((size_t)N_GRAPHS * H + 255) / 256, 256, 0, stream>>>(
        gictx, ghr, gAb, out, N_GRAPHS);
}

// Round 8
// 936.949 us; speedup vs baseline: 1.1527x; 1.1527x over previous
//
#include <hip/hip_runtime.h>
#include <hip/hip_bf16.h>
#include <math.h>

#define N_NODES 50000
#define N_EDGES 640000
#define N_GRAPHS 2000
#define FN 64
#define FE 16
#define H 128
#define NL 2
#define DPW 4
#define SCB 1024

typedef __attribute__((ext_vector_type(8))) short short8;
typedef __attribute__((ext_vector_type(4))) float float4v;
typedef __hip_bfloat16 bf16;

// ---------------- static workspace ----------------
static constexpr size_t AL = 256;
static constexpr size_t alup(size_t x) { return (x + AL - 1) & ~(AL - 1); }

static constexpr size_t SZ_HF    = (size_t)N_NODES * H * 4;
static constexpr size_t SZ_HB    = (size_t)N_NODES * H * 2;
static constexpr size_t SZ_XB    = (size_t)N_NODES * FN * 2;
static constexpr size_t SZ_PQMB  = (size_t)N_NODES * 384 * 2;
static constexpr size_t SZ_GH    = (size_t)N_NODES * 384 * 4;
static constexpr size_t SZ_GI    = (size_t)N_NODES * 384 * 4;
static constexpr size_t SZ_AGB   = (size_t)N_NODES * H * 2;
static constexpr size_t SZ_NF    = (size_t)N_NODES * 4;
static constexpr size_t SZ_WT    = (size_t)768 * 128 * 2;
static constexpr size_t SZ_WIHT  = (size_t)384 * 128 * 2;
static constexpr size_t SZ_EMBT  = (size_t)128 * 64 * 2;
static constexpr size_t SZ_BBIG  = (size_t)768 * 4;
static constexpr size_t SZ_G128  = (size_t)N_GRAPHS * 128 * 4;
static constexpr size_t SZ_G384  = (size_t)N_GRAPHS * 384 * 4;
static constexpr size_t SZ_GF    = (size_t)N_GRAPHS * 4;
static constexpr size_t SZ_CSE   = (size_t)N_EDGES * 8;
static constexpr size_t SZ_BSUM  = 256 * 4;

static constexpr size_t OFF_H0    = 0;
static constexpr size_t OFF_H1    = alup(OFF_H0 + SZ_HF);
static constexpr size_t OFF_H0B   = alup(OFF_H1 + SZ_HF);
static constexpr size_t OFF_H1B   = alup(OFF_H0B + SZ_HB);
static constexpr size_t OFF_XB    = alup(OFF_H1B + SZ_HB);
static constexpr size_t OFF_PQMB  = alup(OFF_XB + SZ_XB);
static constexpr size_t OFF_GH    = alup(OFF_PQMB + SZ_PQMB);
static constexpr size_t OFF_GI    = alup(OFF_GH + SZ_GH);
static constexpr size_t OFF_AGB   = alup(OFF_GI + SZ_GI);
static constexpr size_t OFF_ES    = alup(OFF_AGB + SZ_AGB);
static constexpr size_t OFF_WT    = alup(OFF_ES + SZ_NF);
static constexpr size_t OFF_WIHT  = alup(OFF_WT + SZ_WT);
static constexpr size_t OFF_EMBT  = alup(OFF_WIHT + SZ_WIHT);
static constexpr size_t OFF_BBIG  = alup(OFF_EMBT + SZ_EMBT);
static constexpr size_t OFF_G0    = alup(OFF_BBIG + SZ_BBIG);
static constexpr size_t OFF_GA    = alup(OFF_G0 + SZ_G128);
static constexpr size_t OFF_CTX   = alup(OFF_GA + SZ_G128);
static constexpr size_t OFF_GICTX = alup(OFF_CTX + SZ_G128);
static constexpr size_t OFF_GHB   = alup(OFF_GICTX + SZ_G384);
static constexpr size_t OFF_GSUM  = alup(OFF_GHB + SZ_G384);
static constexpr size_t OFF_DEG   = alup(OFF_GSUM + SZ_GF);
static constexpr size_t OFF_OFFS  = alup(OFF_DEG + SZ_NF);
static constexpr size_t OFF_CUR   = alup(OFF_OFFS + SZ_NF + 4);
static constexpr size_t OFF_CSE   = alup(OFF_CUR + SZ_NF);
static constexpr size_t OFF_GHIST = alup(OFF_CSE + SZ_CSE);
static constexpr size_t OFF_GOFFS = alup(OFF_GHIST + SZ_GF);
static constexpr size_t OFF_BSUM  = alup(OFF_GOFFS + SZ_GF + 4);
static constexpr size_t TOTAL_WS  = alup(OFF_BSUM + SZ_BSUM);

__device__ unsigned char g_afp_ws[TOTAL_WS];

__device__ inline float bf2f(unsigned short u) {
    unsigned int x = ((unsigned int)u) << 16;
    return __uint_as_float(x);
}

// ---------------- MFMA bf16 GEMM (compile-time K, fully unrolled) ----------------
// mode bit0: relu. bit1: split768 -> Cb (c<384) / Cb2 (c>=384), bf16. bit2: dual f32+bf16.
template<int K>
__global__ __launch_bounds__(256) void gemm_mfma(
    const bf16* __restrict__ Abf, const bf16* __restrict__ Btbf,
    const float* __restrict__ bias, float* __restrict__ C,
    bf16* __restrict__ Cb, bf16* __restrict__ Cb2,
    int M, int Ncol, int mode)
{
    const unsigned short* A  = (const unsigned short*)Abf;
    const unsigned short* Bt = (const unsigned short*)Btbf;
    const int l  = threadIdx.x & 63;
    const int w  = threadIdx.x >> 6;
    const int wm = w >> 1, wn = w & 1;
    const int row0 = blockIdx.x * 64 + wm * 32;
    const int col0 = blockIdx.y * 64 + wn * 32;
    const int lr = l & 15;
    const int lk = (l >> 4) * 8;
    float4v acc[2][2] = {};
    #pragma unroll
    for (int k0 = 0; k0 < K; k0 += 32) {
        short8 a[2], b[2];
        #pragma unroll
        for (int i = 0; i < 2; ++i) {
            int r = row0 + i * 16 + lr;
            if (r >= M) r = M - 1;
            a[i] = *(const short8*)(A + (size_t)r * K + k0 + lk);
        }
        #pragma unroll
        for (int j = 0; j < 2; ++j) {
            int c = col0 + j * 16 + lr;
            b[j] = *(const short8*)(Bt + (size_t)c * K + k0 + lk);
        }
        #pragma unroll
        for (int i = 0; i < 2; ++i)
            #pragma unroll
            for (int j = 0; j < 2; ++j)
                acc[i][j] = __builtin_amdgcn_mfma_f32_16x16x32_bf16(a[i], b[j], acc[i][j], 0, 0, 0);
    }
    const int orow = (l >> 4) * 4;
    const int ocol = l & 15;
    #pragma unroll
    for (int i = 0; i < 2; ++i) {
        #pragma unroll
        for (int j = 0; j < 2; ++j) {
            const int gc = col0 + j * 16 + ocol;
            const float bi = bias ? bias[gc] : 0.f;
            #pragma unroll
            for (int r = 0; r < 4; ++r) {
                const int gr = row0 + i * 16 + orow + r;
                if (gr >= M) continue;
                float v = acc[i][j][r] + bi;
                if (mode & 1) v = fmaxf(v, 0.f);
                if (mode & 2) {
                    if (gc < 384) Cb[(size_t)gr * 384 + gc] = __float2bfloat16(v);
                    else          Cb2[(size_t)gr * 384 + (gc - 384)] = __float2bfloat16(v);
                } else {
                    C[(size_t)gr * Ncol + gc] = v;
                    if (mode & 4) Cb[(size_t)gr * Ncol + gc] = __float2bfloat16(v);
                }
            }
        }
    }
}

// ---------------- fused gi-GEMM + GRU ----------------
__global__ __launch_bounds__(256) void gemm_gru(
    const bf16* __restrict__ Abf, const bf16* __restrict__ Btbf,
    const float* __restrict__ bias, const bf16* __restrict__ ghb,
    const float* __restrict__ hold, float* __restrict__ hnew,
    bf16* __restrict__ hnewb, int M)
{
    const unsigned short* A  = (const unsigned short*)Abf;
    const unsigned short* Bt = (const unsigned short*)Btbf;
    const unsigned short* gh = (const unsigned short*)ghb;
    const int l  = threadIdx.x & 63;
    const int w  = threadIdx.x >> 6;
    const int row0 = blockIdx.x * 64 + w * 16;
    const int lr = l & 15;
    const int lk = (l >> 4) * 8;
    float4v acc[24] = {};
    #pragma unroll
    for (int k0 = 0; k0 < 128; k0 += 32) {
        int r = row0 + lr;
        if (r >= M) r = M - 1;
        short8 a = *(const short8*)(A + (size_t)r * 128 + k0 + lk);
        #pragma unroll
        for (int j = 0; j < 24; ++j) {
            short8 b = *(const short8*)(Bt + (size_t)(j * 16 + lr) * 128 + k0 + lk);
            acc[j] = __builtin_amdgcn_mfma_f32_16x16x32_bf16(a, b, acc[j], 0, 0, 0);
        }
    }
    const int orow = (l >> 4) * 4;
    const int ocol = l & 15;
    #pragma unroll
    for (int a_ = 0; a_ < 8; ++a_) {
        const int c = a_ * 16 + ocol;
        const float bir = bias[c], biz = bias[c + 128], bin = bias[c + 256];
        #pragma unroll
        for (int r = 0; r < 4; ++r) {
            const int gr = row0 + orow + r;
            if (gr >= M) continue;
            float ir = acc[a_][r] + bir;
            float iz = acc[a_ + 8][r] + biz;
            float in = acc[a_ + 16][r] + bin;
            const unsigned short* ghp = gh + (size_t)gr * 384;
            float hr = bf2f(ghp[c]);
            float hz = bf2f(ghp[128 + c]);
            float hn = bf2f(ghp[256 + c]);
            float rg = 1.f / (1.f + __expf(-(ir + hr)));
            float zg = 1.f / (1.f + __expf(-(iz + hz)));
            float ng = tanhf(in + rg * hn);
            float hv = hold[(size_t)gr * 128 + c];
            float o = (1.f - zg) * ng + zg * hv;
            hnew[(size_t)gr * 128 + c] = o;
            hnewb[(size_t)gr * 128 + c] = __float2bfloat16(o);
        }
    }
}

// ---------------- f32 GEMM (small readout matmuls only) ----------------
#define GBM 64
#define GBN 64
#define GBK 32
__global__ __launch_bounds__(256) void gemm_f32(
    const float* __restrict__ A, const float* __restrict__ B,
    const float* __restrict__ bias, float* __restrict__ C,
    int M, int K, int Ncol)
{
    __shared__ float As[GBK][GBM + 4];
    __shared__ float Bs[GBK][GBN + 4];
    const int tx = threadIdx.x & 15;
    const int ty = threadIdx.x >> 4;
    const int row0 = blockIdx.x * GBM;
    const int col0 = blockIdx.y * GBN;
    float acc[4][4] = {};
    for (int k0 = 0; k0 < K; k0 += GBK) {
        for (int i = threadIdx.x; i < GBM * GBK; i += 256) {
            int r = i / GBK, c = i % GBK;
            float v = 0.f;
            if (row0 + r < M) v = A[(size_t)(row0 + r) * K + k0 + c];
            As[c][r] = v;
        }
        for (int i = threadIdx.x; i < GBK * GBN; i += 256) {
            int r = i / GBN, c = i % GBN;
            float v = 0.f;
            if (col0 + c < Ncol) v = B[(size_t)(k0 + r) * Ncol + col0 + c];
            Bs[r][c] = v;
        }
        __syncthreads();
        #pragma unroll
        for (int k = 0; k < GBK; ++k) {
            float a[4], b[4];
            #pragma unroll
            for (int i = 0; i < 4; ++i) a[i] = As[k][ty * 4 + i];
            #pragma unroll
            for (int j = 0; j < 4; ++j) b[j] = Bs[k][tx * 4 + j];
            #pragma unroll
            for (int i = 0; i < 4; ++i)
                #pragma unroll
                for (int j = 0; j < 4; ++j)
                    acc[i][j] = fmaf(a[i], b[j], acc[i][j]);
        }
        __syncthreads();
    }
    #pragma unroll
    for (int i = 0; i < 4; ++i) {
        int r = row0 + ty * 4 + i;
        if (r >= M) continue;
        #pragma unroll
        for (int j = 0; j < 4; ++j) {
            int c = col0 + tx * 4 + j;
            if (c >= Ncol) continue;
            C[(size_t)r * Ncol + c] = acc[i][j] + (bias ? bias[c] : 0.f);
        }
    }
}

// ---------------- weight packing ----------------
__global__ void pack_weights_bt(const float* __restrict__ attW1,
                                const float* __restrict__ mlpW,
                                const float* __restrict__ whh,
                                const float* __restrict__ attb1,
                                const float* __restrict__ mlpb,
                                const float* __restrict__ bhh,
                                bf16* __restrict__ wt, float* __restrict__ bbig)
{
    int idx = blockIdx.x * blockDim.x + threadIdx.x;
    if (idx >= 768 * 128) return;
    int j = idx >> 7, k = idx & 127;
    float v;
    if (j < 128)      v = attW1[k * 128 + j];
    else if (j < 256) v = attW1[(128 + k) * 128 + (j - 128)];
    else if (j < 384) v = mlpW[k * 128 + (j - 256)];
    else              v = whh[k * 384 + (j - 384)];
    wt[idx] = __float2bfloat16(v);
    if (k == 0) {
        float b;
        if (j < 128)      b = attb1[j];
        else if (j < 256) b = 0.f;
        else if (j < 384) b = mlpb[j - 256];
        else              b = bhh[j - 384];
        bbig[j] = b;
    }
}

__global__ void transpose_cast(const float* __restrict__ in, bf16* __restrict__ out,
                               int K, int Ncol)
{
    int idx = blockIdx.x * blockDim.x + threadIdx.x;
    if (idx >= K * Ncol) return;
    int k = idx / Ncol, j = idx % Ncol;
    out[(size_t)j * K + k] = __float2bfloat16(in[idx]);
}

__global__ void cast_bf16_kernel(const float* __restrict__ in, bf16* __restrict__ out, int n)
{
    int idx = blockIdx.x * blockDim.x + threadIdx.x;
    if (idx < n) out[idx] = __float2bfloat16(in[idx]);
}

// ---------------- CSR build ----------------
__global__ void hist_dst_kernel(const int* __restrict__ ei, int* __restrict__ deg) {
    int e = blockIdx.x * blockDim.x + threadIdx.x;
    if (e < N_EDGES) atomicAdd(&deg[ei[N_EDGES + e]], 1);
}
__global__ void hist_batch_kernel(const int* __restrict__ batch, int* __restrict__ hist) {
    int n = blockIdx.x * blockDim.x + threadIdx.x;
    if (n < N_NODES) atomicAdd(&hist[batch[n]], 1);
}

// hierarchical exclusive scan: local -> block sums -> add
__global__ __launch_bounds__(1024) void scan_local(const int* __restrict__ in,
        int* __restrict__ out, int* __restrict__ bsum, int n)
{
    __shared__ int buf[SCB];
    int i = blockIdx.x * SCB + threadIdx.x;
    int v = (i < n) ? in[i] : 0;
    buf[threadIdx.x] = v;
    __syncthreads();
    #pragma unroll
    for (int off = 1; off < SCB; off <<= 1) {
        int t = (threadIdx.x >= off) ? buf[threadIdx.x - off] : 0;
        __syncthreads();
        buf[threadIdx.x] += t;
        __syncthreads();
    }
    if (i < n) out[i] = buf[threadIdx.x] - v;
    if (threadIdx.x == SCB - 1) bsum[blockIdx.x] = buf[SCB - 1];
}
__global__ __launch_bounds__(1024) void scan_bsum(int* __restrict__ bsum, int nb,
        int* __restrict__ total_dst)
{
    __shared__ int buf[SCB];
    int v = (threadIdx.x < nb) ? bsum[threadIdx.x] : 0;
    buf[threadIdx.x] = v;
    __syncthreads();
    #pragma unroll
    for (int off = 1; off < SCB; off <<= 1) {
        int t = (threadIdx.x >= off) ? buf[threadIdx.x - off] : 0;
        __syncthreads();
        buf[threadIdx.x] += t;
        __syncthreads();
    }
    if (threadIdx.x < nb) bsum[threadIdx.x] = buf[threadIdx.x] - v;
    if (threadIdx.x == 0) *total_dst = buf[SCB - 1];
}
__global__ __launch_bounds__(1024) void scan_addoff(int* __restrict__ out,
        const int* __restrict__ bsum, int n)
{
    int i = blockIdx.x * SCB + threadIdx.x;
    if (i < n) out[i] += bsum[blockIdx.x];
}

__global__ void scatter_cse_kernel(const int* __restrict__ ei, const int* __restrict__ offs,
                                   int* __restrict__ cur, int2* __restrict__ cse) {
    int e = blockIdx.x * blockDim.x + threadIdx.x;
    if (e >= N_EDGES) return;
    int d = ei[N_EDGES + e];
    int pos = offs[d] + atomicAdd(&cur[d], 1);
    cse[pos] = make_int2(ei[e], e);
}

// ---------------- fused edge attention + aggregation ----------------
// wave per DPW consecutive dsts; 1-slot prefetch + deferred-score pipeline:
// the shfl-reduce/exp of edge i-1 overlaps edge i's FMA block.
__global__ __launch_bounds__(256, 2) void edge_fused_kernel(
    const bf16* __restrict__ pqm_b,
    const int2* __restrict__ cse, const float* __restrict__ ea,
    const float* __restrict__ w1c_g, const float* __restrict__ w2_g,
    const float* __restrict__ b2_g, const float* __restrict__ mlpw2_g,
    const int* __restrict__ offs, bf16* __restrict__ aggrb)
{
    const unsigned short* pqm = (const unsigned short*)pqm_b;
    const int wv = threadIdx.x >> 6, lane = threadIdx.x & 63;
    const int c0 = lane * 2;
    float w1r[16][2], wmr[16][2];
    #pragma unroll
    for (int k = 0; k < 16; ++k) {
        w1r[k][0] = w1c_g[k * 128 + c0];
        w1r[k][1] = w1c_g[k * 128 + c0 + 1];
        wmr[k][0] = mlpw2_g[k * 128 + c0];
        wmr[k][1] = mlpw2_g[k * 128 + c0 + 1];
    }
    const float w20 = w2_g[c0], w21 = w2_g[c0 + 1];
    const float b2 = b2_g[0];
    const int dbase = __builtin_amdgcn_readfirstlane((blockIdx.x * 4 + wv) * DPW);

    for (int rep = 0; rep < DPW; ++rep) {
        const int d = dbase + rep;
        if (d >= N_NODES) break;
        const ushort2 pu = *(const ushort2*)(pqm + (size_t)d * 384 + c0);
        const float p0 = bf2f(pu.x), p1 = bf2f(pu.y);
        float acc0 = 0.f, acc1 = 0.f, ssum = 0.f;
        const int b = offs[d], en = offs[d + 1];
        if (b < en) {
            int2 se = cse[b];
            const unsigned short* ps = pqm + (size_t)se.x * 384;
            ushort2 qu = *(const ushort2*)(ps + 128 + c0);
            ushort2 mu = *(const ushort2*)(ps + 256 + c0);
            const float4* eap = (const float4*)(ea + (size_t)se.y * 16);
            float4 e0 = eap[0], e1 = eap[1], e2 = eap[2], e3 = eap[3];
            float sp_p = 0.f, m0_p = 0.f, m1_p = 0.f, gate = 0.f;
            for (int i = b; i < en; ++i) {
                // snapshot current edge
                float t0 = p0 + bf2f(qu.x), t1 = p1 + bf2f(qu.y);
                float m0 = bf2f(mu.x), m1 = bf2f(mu.y);
                float er[16];
                er[0]=e0.x; er[1]=e0.y; er[2]=e0.z; er[3]=e0.w;
                er[4]=e1.x; er[5]=e1.y; er[6]=e1.z; er[7]=e1.w;
                er[8]=e2.x; er[9]=e2.y; er[10]=e2.z; er[11]=e2.w;
                er[12]=e3.x; er[13]=e3.y; er[14]=e3.z; er[15]=e3.w;
                // issue loads for edge i+1
                if (i + 1 < en) {
                    se = cse[i + 1];
                    const unsigned short* psn = pqm + (size_t)se.x * 384;
                    qu = *(const ushort2*)(psn + 128 + c0);
                    mu = *(const ushort2*)(psn + 256 + c0);
                    const float4* eapn = (const float4*)(ea + (size_t)se.y * 16);
                    e0 = eapn[0]; e1 = eapn[1]; e2 = eapn[2]; e3 = eapn[3];
                }
                // finish PREVIOUS edge's score (shfl chain overlaps FMAs below)
                float sps = sp_p;
                #pragma unroll
                for (int off = 32; off; off >>= 1) sps += __shfl_xor(sps, off);
                const float ex = gate * __expf(sps + b2);
                ssum += ex;
                acc0 = fmaf(ex, fmaxf(m0_p, 0.f), acc0);
                acc1 = fmaf(ex, fmaxf(m1_p, 0.f), acc1);
                // FMAs for current edge
                #pragma unroll
                for (int k = 0; k < 16; ++k) {
                    t0 = fmaf(er[k], w1r[k][0], t0);
                    t1 = fmaf(er[k], w1r[k][1], t1);
                    m0 = fmaf(er[k], wmr[k][0], m0);
                    m1 = fmaf(er[k], wmr[k][1], m1);
                }
                float a0 = (t0 > 0.f) ? t0 : 0.2f * t0;
                float a1 = (t1 > 0.f) ? t1 : 0.2f * t1;
                sp_p = a0 * w20 + a1 * w21;
                m0_p = m0; m1_p = m1;
                gate = 1.f;
            }
            // epilogue: last edge's score
            float sps = sp_p;
            #pragma unroll
            for (int off = 32; off; off >>= 1) sps += __shfl_xor(sps, off);
            const float ex = __expf(sps + b2);
            ssum += ex;
            acc0 = fmaf(ex, fmaxf(m0_p, 0.f), acc0);
            acc1 = fmaf(ex, fmaxf(m1_p, 0.f), acc1);
        }
        const float inv = 1.f / (ssum + 1e-16f);
        bf16* outp = aggrb + (size_t)d * 128 + c0;
        outp[0] = __float2bfloat16(acc0 * inv);
        outp[1] = __float2bfloat16(acc1 * inv);
    }
}

// ---------------- GRU elementwise (readout graph GRU only) ----------------
__global__ void gru_elem_kernel(const float* __restrict__ gi,
                                const float* __restrict__ gh,
                                const float* __restrict__ hold, float* __restrict__ hnew,
                                int rows)
{
    int idx = blockIdx.x * blockDim.x + threadIdx.x;
    if (idx >= rows * H) return;
    int r = idx >> 7, c = idx & 127;
    float ir = gi[(size_t)r * 384 + c];
    float iz = gi[(size_t)r * 384 + 128 + c];
    float in = gi[(size_t)r * 384 + 256 + c];
    float hr = gh[(size_t)r * 384 + c];
    float hz = gh[(size_t)r * 384 + 128 + c];
    float hn = gh[(size_t)r * 384 + 256 + c];
    float rg = 1.f / (1.f + __expf(-(ir + hr)));
    float zg = 1.f / (1.f + __expf(-(iz + hz)));
    float ng = tanhf(in + rg * hn);
    float hv = hold[idx];
    hnew[idx] = (1.f - zg) * ng + zg * hv;
}

// ---------------- graph pooling / readout ----------------
__global__ __launch_bounds__(128) void graph_pool_sum(
    const float* __restrict__ h, const int* __restrict__ goffs, float* __restrict__ g0)
{
    int g = blockIdx.x, c = threadIdx.x;
    int b = goffs[g], e2 = goffs[g + 1];
    float acc = 0.f;
    for (int i = b; i < e2; ++i) acc += h[(size_t)i * 128 + c];
    g0[(size_t)g * 128 + c] = acc;
}

__global__ __launch_bounds__(256) void node_score2_kernel(
    const float* __restrict__ hW1, const float* __restrict__ W2,
    const float* __restrict__ b2, const int* __restrict__ batch,
    float* __restrict__ es, float* __restrict__ gsum)
{
    const int wv = threadIdx.x >> 6, lane = threadIdx.x & 63;
    const int n = blockIdx.x * 4 + wv;
    if (n >= N_NODES) return;
    const int c0 = lane * 2;
    float sp = tanhf(hW1[(size_t)n * 128 + c0]) * W2[c0]
             + tanhf(hW1[(size_t)n * 128 + c0 + 1]) * W2[c0 + 1];
    #pragma unroll
    for (int off = 32; off; off >>= 1) sp += __shfl_xor(sp, off);
    if (lane == 0) {
        float ex = __expf(sp + b2[0]);
        es[n] = ex;
        atomicAdd(&gsum[batch[n]], ex);
    }
}

__global__ __launch_bounds__(128) void graph_ctx_kernel(
    const float* __restrict__ h, const int* __restrict__ goffs,
    const float* __restrict__ es, const float* __restrict__ gsum,
    float* __restrict__ ctx)
{
    int g = blockIdx.x, c = threadIdx.x;
    float invs = 1.f / (gsum[g] + 1e-16f);
    int b = goffs[g], e2 = goffs[g + 1];
    float acc = 0.f;
    for (int i = b; i < e2; ++i) acc = fmaf(es[i] * invs, h[(size_t)i * 128 + c], acc);
    ctx[(size_t)g * 128 + c] = acc;
}

extern "C" void kernel_launch(void* const* d_in, const int* in_sizes, int n_in,
                              void* d_out, int out_size, void* d_ws, size_t ws_size,
                              hipStream_t stream) {
    const float* x      = (const float*)d_in[0];
    const int*   ei     = (const int*)d_in[1];
    const float* ea     = (const float*)d_in[2];
    const int*   batch  = (const int*)d_in[3];
    const float* embW   = (const float*)d_in[4];
    const float* embB   = (const float*)d_in[5];
    const float* attW1  = (const float*)d_in[6];
    const float* attb1  = (const float*)d_in[7];
    const float* attW2  = (const float*)d_in[8];
    const float* attb2  = (const float*)d_in[9];
    const float* mlpW   = (const float*)d_in[10];
    const float* mlpb   = (const float*)d_in[11];
    const float* gWih   = (const float*)d_in[12];
    const float* gWhh   = (const float*)d_in[13];
    const float* gbih   = (const float*)d_in[14];
    const float* gbhh   = (const float*)d_in[15];
    const float* gattW1 = (const float*)d_in[16];
    const float* gattb1 = (const float*)d_in[17];
    const float* gattW2 = (const float*)d_in[18];
    const float* gattb2 = (const float*)d_in[19];
    const float* ggWih  = (const float*)d_in[20];
    const float* ggWhh  = (const float*)d_in[21];
    const float* ggbih  = (const float*)d_in[22];
    const float* ggbhh  = (const float*)d_in[23];
    float* out = (float*)d_out;

    void* basep = nullptr;
    (void)hipGetSymbolAddress(&basep, HIP_SYMBOL(g_afp_ws));
    char* base = (char*)basep;
    float* h0    = (float*)(base + OFF_H0);
    float* h1    = (float*)(base + OFF_H1);
    bf16*  h0b   = (bf16*)(base + OFF_H0B);
    bf16*  h1b   = (bf16*)(base + OFF_H1B);
    bf16*  xb    = (bf16*)(base + OFF_XB);
    bf16*  pqmb  = (bf16*)(base + OFF_PQMB);
    bf16*  ghx   = (bf16*)(base + OFF_GH);
    float* hW1   = (float*)(base + OFF_GI);
    bf16*  aggrb = (bf16*)(base + OFF_AGB);
    float* es    = (float*)(base + OFF_ES);
    bf16*  wt    = (bf16*)(base + OFF_WT);
    bf16*  wiht  = (bf16*)(base + OFF_WIHT);
    bf16*  embt  = (bf16*)(base + OFF_EMBT);
    float* bbig  = (float*)(base + OFF_BBIG);
    float* g0b   = (float*)(base + OFF_G0);
    float* gAb   = (float*)(base + OFF_GA);
    float* ctx   = (float*)(base + OFF_CTX);
    float* gictx = (float*)(base + OFF_GICTX);
    float* ghr   = (float*)(base + OFF_GHB);
    float* gsum  = (float*)(base + OFF_GSUM);
    int*   deg   = (int*)(base + OFF_DEG);
    int*   offs  = (int*)(base + OFF_OFFS);
    int*   cur   = (int*)(base + OFF_CUR);
    int2*  cse   = (int2*)(base + OFF_CSE);
    int*   ghist = (int*)(base + OFF_GHIST);
    int*   goffs = (int*)(base + OFF_GOFFS);
    int*   bsum  = (int*)(base + OFF_BSUM);

    (void)hipMemsetAsync(deg, 0, SZ_NF, stream);
    (void)hipMemsetAsync(cur, 0, SZ_NF, stream);
    (void)hipMemsetAsync(ghist, 0, SZ_GF, stream);
    (void)hipMemsetAsync(gsum, 0, SZ_GF, stream);

    const int nbN = (N_NODES + SCB - 1) / SCB;
    const int nbG = (N_GRAPHS + SCB - 1) / SCB;

    hist_dst_kernel<<<(N_EDGES + 255) / 256, 256, 0, stream>>>(ei, deg);
    scan_local<<<nbN, SCB, 0, stream>>>(deg, offs, bsum, N_NODES);
    scan_bsum<<<1, SCB, 0, stream>>>(bsum, nbN, offs + N_NODES);
    scan_addoff<<<nbN, SCB, 0, stream>>>(offs, bsum, N_NODES);
    scatter_cse_kernel<<<(N_EDGES + 255) / 256, 256, 0, stream>>>(ei, offs, cur, cse);
    hist_batch_kernel<<<(N_NODES + 255) / 256, 256, 0, stream>>>(batch, ghist);
    scan_local<<<nbG, SCB, 0, stream>>>(ghist, goffs, bsum, N_GRAPHS);
    scan_bsum<<<1, SCB, 0, stream>>>(bsum, nbG, goffs + N_GRAPHS);
    scan_addoff<<<nbG, SCB, 0, stream>>>(goffs, bsum, N_GRAPHS);

    cast_bf16_kernel<<<(N_NODES * FN + 255) / 256, 256, 0, stream>>>(x, xb, N_NODES * FN);
    transpose_cast<<<(FN * 128 + 255) / 256, 256, 0, stream>>>(embW, embt, FN, 128);

    {
        dim3 g((N_NODES + 63) / 64, 128 / 64);
        gemm_mfma<64><<<g, 256, 0, stream>>>(xb, embt, embB, h0, h0b, nullptr,
                                             N_NODES, 128, 1 | 4);
    }

    float* hcur = h0;  bf16* hcurb = h0b;
    float* hnext = h1; bf16* hnextb = h1b;
    for (int l = 0; l < NL; ++l) {
        pack_weights_bt<<<(768 * 128 + 255) / 256, 256, 0, stream>>>(
            attW1 + (size_t)l * 272 * 128, mlpW + (size_t)l * 144 * 128,
            gWhh + (size_t)l * 128 * 384, attb1 + l * 128, mlpb + l * 128,
            gbhh + l * 384, wt, bbig);
        {
            dim3 g((N_NODES + 63) / 64, 768 / 64);
            gemm_mfma<128><<<g, 256, 0, stream>>>(hcurb, wt, bbig, nullptr, pqmb, ghx,
                                                  N_NODES, 768, 2);
        }
        edge_fused_kernel<<<(N_NODES + 4 * DPW - 1) / (4 * DPW), 256, 0, stream>>>(
            pqmb, cse, ea, attW1 + (size_t)l * 272 * 128 + 256 * 128,
            attW2 + (size_t)l * 128, attb2 + l,
            mlpW + (size_t)l * 144 * 128 + 128 * 128,
            offs, aggrb);
        transpose_cast<<<(128 * 384 + 255) / 256, 256, 0, stream>>>(
            gWih + (size_t)l * 128 * 384, wiht, 128, 384);
        gemm_gru<<<(N_NODES + 63) / 64, 256, 0, stream>>>(
            aggrb, wiht, gbih + l * 384, ghx, hcur, hnext, hnextb, N_NODES);
        float* t = hcur; hcur = hnext; hnext = t;
        bf16* tb = hcurb; hcurb = hnextb; hnextb = tb;
    }

    // readout (h fixed across T -> ctx computed once)
    graph_pool_sum<<<N_GRAPHS, 128, 0, stream>>>(hcur, goffs, g0b);
    transpose_cast<<<(128 * 128 + 255) / 256, 256, 0, stream>>>(gattW1, wiht, 128, 128);
    {
        dim3 g((N_NODES + 63) / 64, 128 / 64);
        gemm_mfma<128><<<g, 256, 0, stream>>>(hcurb, wiht, gattb1, hW1, nullptr, nullptr,
                                              N_NODES, 128, 0);
    }
    node_score2_kernel<<<(N_NODES + 3) / 4, 256, 0, stream>>>(
        hW1, gattW2, gattb2, batch, es, gsum);
    graph_ctx_kernel<<<N_GRAPHS, 128, 0, stream>>>(hcur, goffs, es, gsum, ctx);

    dim3 gg((N_GRAPHS + 63) / 64, 384 / 64);
    gemm_f32<<<gg, 256, 0, stream>>>(ctx, ggWih, ggbih, gictx, N_GRAPHS, H, 384);
    gemm_f32<<<gg, 256, 0, stream>>>(g0b, ggWhh, ggbhh, ghr, N_GRAPHS, H, 384);
    gru_elem_kernel<<<((size_t)N_GRAPHS * H + 255) / 256, 256, 0, stream>>>(
        gictx, ghr, g0b, gAb, N_GRAPHS);
    gemm_f32<<<gg, 256, 0, stream>>>(gAb, ggWhh, ggbhh, ghr, N_GRAPHS, H, 384);
    gru_elem_kernel<<<((size_t)N_GRAPHS * H + 255) / 256, 256, 0, stream>>>(
        gictx, ghr, gAb, out, N_GRAPHS);
}

// Round 9
// 916.297 us; speedup vs baseline: 1.1787x; 1.0225x over previous
//
#include <hip/hip_runtime.h>
#include <hip/hip_bf16.h>
#include <math.h>

#define N_NODES 50000
#define N_EDGES 640000
#define N_GRAPHS 2000
#define FN 64
#define FE 16
#define H 128
#define NL 2
#define SCB 1024

typedef __attribute__((ext_vector_type(8))) short short8;
typedef __attribute__((ext_vector_type(4))) float float4v;
typedef __hip_bfloat16 bf16;

// ---------------- static workspace ----------------
static constexpr size_t AL = 256;
static constexpr size_t alup(size_t x) { return (x + AL - 1) & ~(AL - 1); }

static constexpr size_t SZ_HF    = (size_t)N_NODES * H * 4;
static constexpr size_t SZ_HB    = (size_t)N_NODES * H * 2;
static constexpr size_t SZ_XB    = (size_t)N_NODES * FN * 2;
static constexpr size_t SZ_PQMB  = (size_t)N_NODES * 384 * 2;
static constexpr size_t SZ_GH    = (size_t)N_NODES * 384 * 4;
static constexpr size_t SZ_GI    = (size_t)N_NODES * 384 * 4;
static constexpr size_t SZ_AGB   = (size_t)N_NODES * H * 2;
static constexpr size_t SZ_NF    = (size_t)N_NODES * 4;
static constexpr size_t SZ_WT    = (size_t)768 * 128 * 2;
static constexpr size_t SZ_WIHT  = (size_t)384 * 128 * 2;
static constexpr size_t SZ_EMBT  = (size_t)128 * 64 * 2;
static constexpr size_t SZ_BBIG  = (size_t)768 * 4;
static constexpr size_t SZ_G128  = (size_t)N_GRAPHS * 128 * 4;
static constexpr size_t SZ_G384  = (size_t)N_GRAPHS * 384 * 4;
static constexpr size_t SZ_GF    = (size_t)N_GRAPHS * 4;
static constexpr size_t SZ_CSE   = (size_t)N_EDGES * 8;
static constexpr size_t SZ_BSUM  = 256 * 4;

static constexpr size_t OFF_H0    = 0;
static constexpr size_t OFF_H1    = alup(OFF_H0 + SZ_HF);
static constexpr size_t OFF_H0B   = alup(OFF_H1 + SZ_HF);
static constexpr size_t OFF_H1B   = alup(OFF_H0B + SZ_HB);
static constexpr size_t OFF_XB    = alup(OFF_H1B + SZ_HB);
static constexpr size_t OFF_PQMB  = alup(OFF_XB + SZ_XB);
static constexpr size_t OFF_GH    = alup(OFF_PQMB + SZ_PQMB);
static constexpr size_t OFF_GI    = alup(OFF_GH + SZ_GH);
static constexpr size_t OFF_AGB   = alup(OFF_GI + SZ_GI);
static constexpr size_t OFF_ES    = alup(OFF_AGB + SZ_AGB);
static constexpr size_t OFF_WT    = alup(OFF_ES + SZ_NF);
static constexpr size_t OFF_WIHT  = alup(OFF_WT + SZ_WT);
static constexpr size_t OFF_EMBT  = alup(OFF_WIHT + SZ_WIHT);
static constexpr size_t OFF_BBIG  = alup(OFF_EMBT + SZ_EMBT);
static constexpr size_t OFF_G0    = alup(OFF_BBIG + SZ_BBIG);
static constexpr size_t OFF_GA    = alup(OFF_G0 + SZ_G128);
static constexpr size_t OFF_CTX   = alup(OFF_GA + SZ_G128);
static constexpr size_t OFF_GICTX = alup(OFF_CTX + SZ_G128);
static constexpr size_t OFF_GHB   = alup(OFF_GICTX + SZ_G384);
static constexpr size_t OFF_GSUM  = alup(OFF_GHB + SZ_G384);
static constexpr size_t OFF_DEG   = alup(OFF_GSUM + SZ_GF);
static constexpr size_t OFF_OFFS  = alup(OFF_DEG + SZ_NF);
static constexpr size_t OFF_CUR   = alup(OFF_OFFS + SZ_NF + 4);
static constexpr size_t OFF_CSE   = alup(OFF_CUR + SZ_NF);
static constexpr size_t OFF_GHIST = alup(OFF_CSE + SZ_CSE);
static constexpr size_t OFF_GOFFS = alup(OFF_GHIST + SZ_GF);
static constexpr size_t OFF_BSUM  = alup(OFF_GOFFS + SZ_GF + 4);
static constexpr size_t TOTAL_WS  = alup(OFF_BSUM + SZ_BSUM);

__device__ unsigned char g_afp_ws[TOTAL_WS];

__device__ inline float bf2f(unsigned short u) {
    unsigned int x = ((unsigned int)u) << 16;
    return __uint_as_float(x);
}

// ---------------- MFMA bf16 GEMM (compile-time K) ----------------
// mode bit0: relu. bit1: split768 -> Cb (c<384) / Cb2 (c>=384) bf16.
// bit2: dual f32+bf16 (stride Ncol). bit3: bf16-only (Cb, stride Ncol).
template<int K>
__global__ __launch_bounds__(256) void gemm_mfma(
    const bf16* __restrict__ Abf, const bf16* __restrict__ Btbf,
    const float* __restrict__ bias, float* __restrict__ C,
    bf16* __restrict__ Cb, bf16* __restrict__ Cb2,
    int M, int Ncol, int mode)
{
    const unsigned short* A  = (const unsigned short*)Abf;
    const unsigned short* Bt = (const unsigned short*)Btbf;
    const int l  = threadIdx.x & 63;
    const int w  = threadIdx.x >> 6;
    const int wm = w >> 1, wn = w & 1;
    const int row0 = blockIdx.x * 64 + wm * 32;
    const int col0 = blockIdx.y * 64 + wn * 32;
    const int lr = l & 15;
    const int lk = (l >> 4) * 8;
    float4v acc[2][2] = {};
    #pragma unroll
    for (int k0 = 0; k0 < K; k0 += 32) {
        short8 a[2], b[2];
        #pragma unroll
        for (int i = 0; i < 2; ++i) {
            int r = row0 + i * 16 + lr;
            if (r >= M) r = M - 1;
            a[i] = *(const short8*)(A + (size_t)r * K + k0 + lk);
        }
        #pragma unroll
        for (int j = 0; j < 2; ++j) {
            int c = col0 + j * 16 + lr;
            b[j] = *(const short8*)(Bt + (size_t)c * K + k0 + lk);
        }
        #pragma unroll
        for (int i = 0; i < 2; ++i)
            #pragma unroll
            for (int j = 0; j < 2; ++j)
                acc[i][j] = __builtin_amdgcn_mfma_f32_16x16x32_bf16(a[i], b[j], acc[i][j], 0, 0, 0);
    }
    const int orow = (l >> 4) * 4;
    const int ocol = l & 15;
    #pragma unroll
    for (int i = 0; i < 2; ++i) {
        #pragma unroll
        for (int j = 0; j < 2; ++j) {
            const int gc = col0 + j * 16 + ocol;
            const float bi = bias ? bias[gc] : 0.f;
            #pragma unroll
            for (int r = 0; r < 4; ++r) {
                const int gr = row0 + i * 16 + orow + r;
                if (gr >= M) continue;
                float v = acc[i][j][r] + bi;
                if (mode & 1) v = fmaxf(v, 0.f);
                if (mode & 2) {
                    if (gc < 384) Cb[(size_t)gr * 384 + gc] = __float2bfloat16(v);
                    else          Cb2[(size_t)gr * 384 + (gc - 384)] = __float2bfloat16(v);
                } else if (mode & 8) {
                    Cb[(size_t)gr * Ncol + gc] = __float2bfloat16(v);
                } else {
                    C[(size_t)gr * Ncol + gc] = v;
                    if (mode & 4) Cb[(size_t)gr * Ncol + gc] = __float2bfloat16(v);
                }
            }
        }
    }
}

// ---------------- fused gi-GEMM + GRU (bf16 h) ----------------
__global__ __launch_bounds__(256) void gemm_gru(
    const bf16* __restrict__ Abf, const bf16* __restrict__ Btbf,
    const float* __restrict__ bias, const bf16* __restrict__ ghb,
    const bf16* __restrict__ holdb, bf16* __restrict__ hnewb, int M)
{
    const unsigned short* A  = (const unsigned short*)Abf;
    const unsigned short* Bt = (const unsigned short*)Btbf;
    const unsigned short* gh = (const unsigned short*)ghb;
    const unsigned short* hold = (const unsigned short*)holdb;
    const int l  = threadIdx.x & 63;
    const int w  = threadIdx.x >> 6;
    const int row0 = blockIdx.x * 64 + w * 16;
    const int lr = l & 15;
    const int lk = (l >> 4) * 8;
    float4v acc[24] = {};
    #pragma unroll
    for (int k0 = 0; k0 < 128; k0 += 32) {
        int r = row0 + lr;
        if (r >= M) r = M - 1;
        short8 a = *(const short8*)(A + (size_t)r * 128 + k0 + lk);
        #pragma unroll
        for (int j = 0; j < 24; ++j) {
            short8 b = *(const short8*)(Bt + (size_t)(j * 16 + lr) * 128 + k0 + lk);
            acc[j] = __builtin_amdgcn_mfma_f32_16x16x32_bf16(a, b, acc[j], 0, 0, 0);
        }
    }
    const int orow = (l >> 4) * 4;
    const int ocol = l & 15;
    #pragma unroll
    for (int a_ = 0; a_ < 8; ++a_) {
        const int c = a_ * 16 + ocol;
        const float bir = bias[c], biz = bias[c + 128], bin = bias[c + 256];
        #pragma unroll
        for (int r = 0; r < 4; ++r) {
            const int gr = row0 + orow + r;
            if (gr >= M) continue;
            float ir = acc[a_][r] + bir;
            float iz = acc[a_ + 8][r] + biz;
            float in = acc[a_ + 16][r] + bin;
            const unsigned short* ghp = gh + (size_t)gr * 384;
            float hr = bf2f(ghp[c]);
            float hz = bf2f(ghp[128 + c]);
            float hn = bf2f(ghp[256 + c]);
            float rg = 1.f / (1.f + __expf(-(ir + hr)));
            float zg = 1.f / (1.f + __expf(-(iz + hz)));
            float ng = tanhf(in + rg * hn);
            float hv = bf2f(hold[(size_t)gr * 128 + c]);
            float o = (1.f - zg) * ng + zg * hv;
            hnewb[(size_t)gr * 128 + c] = __float2bfloat16(o);
        }
    }
}

// ---------------- f32 GEMM (small readout matmuls only) ----------------
#define GBM 64
#define GBN 64
#define GBK 32
__global__ __launch_bounds__(256) void gemm_f32(
    const float* __restrict__ A, const float* __restrict__ B,
    const float* __restrict__ bias, float* __restrict__ C,
    int M, int K, int Ncol)
{
    __shared__ float As[GBK][GBM + 4];
    __shared__ float Bs[GBK][GBN + 4];
    const int tx = threadIdx.x & 15;
    const int ty = threadIdx.x >> 4;
    const int row0 = blockIdx.x * GBM;
    const int col0 = blockIdx.y * GBN;
    float acc[4][4] = {};
    for (int k0 = 0; k0 < K; k0 += GBK) {
        for (int i = threadIdx.x; i < GBM * GBK; i += 256) {
            int r = i / GBK, c = i % GBK;
            float v = 0.f;
            if (row0 + r < M) v = A[(size_t)(row0 + r) * K + k0 + c];
            As[c][r] = v;
        }
        for (int i = threadIdx.x; i < GBK * GBN; i += 256) {
            int r = i / GBN, c = i % GBN;
            float v = 0.f;
            if (col0 + c < Ncol) v = B[(size_t)(k0 + r) * Ncol + col0 + c];
            Bs[r][c] = v;
        }
        __syncthreads();
        #pragma unroll
        for (int k = 0; k < GBK; ++k) {
            float a[4], b[4];
            #pragma unroll
            for (int i = 0; i < 4; ++i) a[i] = As[k][ty * 4 + i];
            #pragma unroll
            for (int j = 0; j < 4; ++j) b[j] = Bs[k][tx * 4 + j];
            #pragma unroll
            for (int i = 0; i < 4; ++i)
                #pragma unroll
                for (int j = 0; j < 4; ++j)
                    acc[i][j] = fmaf(a[i], b[j], acc[i][j]);
        }
        __syncthreads();
    }
    #pragma unroll
    for (int i = 0; i < 4; ++i) {
        int r = row0 + ty * 4 + i;
        if (r >= M) continue;
        #pragma unroll
        for (int j = 0; j < 4; ++j) {
            int c = col0 + tx * 4 + j;
            if (c >= Ncol) continue;
            C[(size_t)r * Ncol + c] = acc[i][j] + (bias ? bias[c] : 0.f);
        }
    }
}

// ---------------- weight packing ----------------
__global__ void pack_weights_bt(const float* __restrict__ attW1,
                                const float* __restrict__ mlpW,
                                const float* __restrict__ whh,
                                const float* __restrict__ attb1,
                                const float* __restrict__ mlpb,
                                const float* __restrict__ bhh,
                                bf16* __restrict__ wt, float* __restrict__ bbig)
{
    int idx = blockIdx.x * blockDim.x + threadIdx.x;
    if (idx >= 768 * 128) return;
    int j = idx >> 7, k = idx & 127;
    float v;
    if (j < 128)      v = attW1[k * 128 + j];
    else if (j < 256) v = attW1[(128 + k) * 128 + (j - 128)];
    else if (j < 384) v = mlpW[k * 128 + (j - 256)];
    else              v = whh[k * 384 + (j - 384)];
    wt[idx] = __float2bfloat16(v);
    if (k == 0) {
        float b;
        if (j < 128)      b = attb1[j];
        else if (j < 256) b = 0.f;
        else if (j < 384) b = mlpb[j - 256];
        else              b = bhh[j - 384];
        bbig[j] = b;
    }
}

__global__ void transpose_cast(const float* __restrict__ in, bf16* __restrict__ out,
                               int K, int Ncol)
{
    int idx = blockIdx.x * blockDim.x + threadIdx.x;
    if (idx >= K * Ncol) return;
    int k = idx / Ncol, j = idx % Ncol;
    out[(size_t)j * K + k] = __float2bfloat16(in[idx]);
}

__global__ void cast_bf16_kernel(const float* __restrict__ in, bf16* __restrict__ out, int n)
{
    int idx = blockIdx.x * blockDim.x + threadIdx.x;
    if (idx < n) out[idx] = __float2bfloat16(in[idx]);
}

// ---------------- CSR build ----------------
__global__ void hist_dst_kernel(const int* __restrict__ ei, int* __restrict__ deg) {
    int e = blockIdx.x * blockDim.x + threadIdx.x;
    if (e < N_EDGES) atomicAdd(&deg[ei[N_EDGES + e]], 1);
}
__global__ void hist_batch_kernel(const int* __restrict__ batch, int* __restrict__ hist) {
    int n = blockIdx.x * blockDim.x + threadIdx.x;
    if (n < N_NODES) atomicAdd(&hist[batch[n]], 1);
}

__global__ __launch_bounds__(1024) void scan_local(const int* __restrict__ in,
        int* __restrict__ out, int* __restrict__ bsum, int n)
{
    __shared__ int buf[SCB];
    int i = blockIdx.x * SCB + threadIdx.x;
    int v = (i < n) ? in[i] : 0;
    buf[threadIdx.x] = v;
    __syncthreads();
    #pragma unroll
    for (int off = 1; off < SCB; off <<= 1) {
        int t = (threadIdx.x >= off) ? buf[threadIdx.x - off] : 0;
        __syncthreads();
        buf[threadIdx.x] += t;
        __syncthreads();
    }
    if (i < n) out[i] = buf[threadIdx.x] - v;
    if (threadIdx.x == SCB - 1) bsum[blockIdx.x] = buf[SCB - 1];
}
__global__ __launch_bounds__(1024) void scan_bsum(int* __restrict__ bsum, int nb,
        int* __restrict__ total_dst)
{
    __shared__ int buf[SCB];
    int v = (threadIdx.x < nb) ? bsum[threadIdx.x] : 0;
    buf[threadIdx.x] = v;
    __syncthreads();
    #pragma unroll
    for (int off = 1; off < SCB; off <<= 1) {
        int t = (threadIdx.x >= off) ? buf[threadIdx.x - off] : 0;
        __syncthreads();
        buf[threadIdx.x] += t;
        __syncthreads();
    }
    if (threadIdx.x < nb) bsum[threadIdx.x] = buf[threadIdx.x] - v;
    if (threadIdx.x == 0) *total_dst = buf[SCB - 1];
}
__global__ __launch_bounds__(1024) void scan_addoff(int* __restrict__ out,
        const int* __restrict__ bsum, int n)
{
    int i = blockIdx.x * SCB + threadIdx.x;
    if (i < n) out[i] += bsum[blockIdx.x];
}

__global__ void scatter_cse_kernel(const int* __restrict__ ei, const int* __restrict__ offs,
                                   int* __restrict__ cur, int2* __restrict__ cse) {
    int e = blockIdx.x * blockDim.x + threadIdx.x;
    if (e >= N_EDGES) return;
    int d = ei[N_EDGES + e];
    int pos = offs[d] + atomicAdd(&cur[d], 1);
    cse[pos] = make_int2(ei[e], e);
}

// ---------------- fused edge attention + aggregation ----------------
// ONE dst per wave (max TLP); 1-slot prefetch pipeline.
__global__ __launch_bounds__(256, 2) void edge_fused_kernel(
    const bf16* __restrict__ pqm_b,
    const int2* __restrict__ cse, const float* __restrict__ ea,
    const float* __restrict__ w1c_g, const float* __restrict__ w2_g,
    const float* __restrict__ b2_g, const float* __restrict__ mlpw2_g,
    const int* __restrict__ offs, bf16* __restrict__ aggrb)
{
    const unsigned short* pqm = (const unsigned short*)pqm_b;
    const int wv = threadIdx.x >> 6, lane = threadIdx.x & 63;
    const int c0 = lane * 2;
    float w1r[16][2], wmr[16][2];
    #pragma unroll
    for (int k = 0; k < 16; ++k) {
        w1r[k][0] = w1c_g[k * 128 + c0];
        w1r[k][1] = w1c_g[k * 128 + c0 + 1];
        wmr[k][0] = mlpw2_g[k * 128 + c0];
        wmr[k][1] = mlpw2_g[k * 128 + c0 + 1];
    }
    const float w20 = w2_g[c0], w21 = w2_g[c0 + 1];
    const float b2 = b2_g[0];
    const int d = __builtin_amdgcn_readfirstlane(blockIdx.x * 4 + wv);
    if (d >= N_NODES) return;

    const ushort2 pu = *(const ushort2*)(pqm + (size_t)d * 384 + c0);
    const float p0 = bf2f(pu.x), p1 = bf2f(pu.y);
    float acc0 = 0.f, acc1 = 0.f, ssum = 0.f;
    const int b = offs[d], en = offs[d + 1];
    if (b < en) {
        int2 se = cse[b];
        const unsigned short* ps = pqm + (size_t)se.x * 384;
        ushort2 qu = *(const ushort2*)(ps + 128 + c0);
        ushort2 mu = *(const ushort2*)(ps + 256 + c0);
        const float4* eap = (const float4*)(ea + (size_t)se.y * 16);
        float4 e0 = eap[0], e1 = eap[1], e2 = eap[2], e3 = eap[3];
        for (int i = b; i < en; ++i) {
            float t0 = p0 + bf2f(qu.x), t1 = p1 + bf2f(qu.y);
            float m0 = bf2f(mu.x), m1 = bf2f(mu.y);
            float er[16];
            er[0]=e0.x; er[1]=e0.y; er[2]=e0.z; er[3]=e0.w;
            er[4]=e1.x; er[5]=e1.y; er[6]=e1.z; er[7]=e1.w;
            er[8]=e2.x; er[9]=e2.y; er[10]=e2.z; er[11]=e2.w;
            er[12]=e3.x; er[13]=e3.y; er[14]=e3.z; er[15]=e3.w;
            if (i + 1 < en) {
                se = cse[i + 1];
                const unsigned short* psn = pqm + (size_t)se.x * 384;
                qu = *(const ushort2*)(psn + 128 + c0);
                mu = *(const ushort2*)(psn + 256 + c0);
                const float4* eapn = (const float4*)(ea + (size_t)se.y * 16);
                e0 = eapn[0]; e1 = eapn[1]; e2 = eapn[2]; e3 = eapn[3];
            }
            #pragma unroll
            for (int k = 0; k < 16; ++k) {
                t0 = fmaf(er[k], w1r[k][0], t0);
                t1 = fmaf(er[k], w1r[k][1], t1);
                m0 = fmaf(er[k], wmr[k][0], m0);
                m1 = fmaf(er[k], wmr[k][1], m1);
            }
            float a0 = (t0 > 0.f) ? t0 : 0.2f * t0;
            float a1 = (t1 > 0.f) ? t1 : 0.2f * t1;
            float sp = a0 * w20 + a1 * w21;
            #pragma unroll
            for (int off = 32; off; off >>= 1) sp += __shfl_xor(sp, off);
            const float ex = __expf(sp + b2);
            ssum += ex;
            acc0 = fmaf(ex, fmaxf(m0, 0.f), acc0);
            acc1 = fmaf(ex, fmaxf(m1, 0.f), acc1);
        }
    }
    const float inv = 1.f / (ssum + 1e-16f);
    bf16* outp = aggrb + (size_t)d * 128 + c0;
    outp[0] = __float2bfloat16(acc0 * inv);
    outp[1] = __float2bfloat16(acc1 * inv);
}

// ---------------- GRU elementwise (readout graph GRU only) ----------------
__global__ void gru_elem_kernel(const float* __restrict__ gi,
                                const float* __restrict__ gh,
                                const float* __restrict__ hold, float* __restrict__ hnew,
                                int rows)
{
    int idx = blockIdx.x * blockDim.x + threadIdx.x;
    if (idx >= rows * H) return;
    int r = idx >> 7, c = idx & 127;
    float ir = gi[(size_t)r * 384 + c];
    float iz = gi[(size_t)r * 384 + 128 + c];
    float in = gi[(size_t)r * 384 + 256 + c];
    float hr = gh[(size_t)r * 384 + c];
    float hz = gh[(size_t)r * 384 + 128 + c];
    float hn = gh[(size_t)r * 384 + 256 + c];
    float rg = 1.f / (1.f + __expf(-(ir + hr)));
    float zg = 1.f / (1.f + __expf(-(iz + hz)));
    float ng = tanhf(in + rg * hn);
    float hv = hold[idx];
    hnew[idx] = (1.f - zg) * ng + zg * hv;
}

// ---------------- graph pooling / readout (bf16 h) ----------------
__global__ __launch_bounds__(128) void graph_pool_sum(
    const bf16* __restrict__ hb, const int* __restrict__ goffs, float* __restrict__ g0)
{
    const unsigned short* h = (const unsigned short*)hb;
    int g = blockIdx.x, c = threadIdx.x;
    int b = goffs[g], e2 = goffs[g + 1];
    float acc = 0.f;
    for (int i = b; i < e2; ++i) acc += bf2f(h[(size_t)i * 128 + c]);
    g0[(size_t)g * 128 + c] = acc;
}

__global__ __launch_bounds__(256) void node_score2_kernel(
    const float* __restrict__ hW1, const float* __restrict__ W2,
    const float* __restrict__ b2, const int* __restrict__ batch,
    float* __restrict__ es, float* __restrict__ gsum)
{
    const int wv = threadIdx.x >> 6, lane = threadIdx.x & 63;
    const int n = blockIdx.x * 4 + wv;
    if (n >= N_NODES) return;
    const int c0 = lane * 2;
    float sp = tanhf(hW1[(size_t)n * 128 + c0]) * W2[c0]
             + tanhf(hW1[(size_t)n * 128 + c0 + 1]) * W2[c0 + 1];
    #pragma unroll
    for (int off = 32; off; off >>= 1) sp += __shfl_xor(sp, off);
    if (lane == 0) {
        float ex = __expf(sp + b2[0]);
        es[n] = ex;
        atomicAdd(&gsum[batch[n]], ex);
    }
}

__global__ __launch_bounds__(128) void graph_ctx_kernel(
    const bf16* __restrict__ hb, const int* __restrict__ goffs,
    const float* __restrict__ es, const float* __restrict__ gsum,
    float* __restrict__ ctx)
{
    const unsigned short* h = (const unsigned short*)hb;
    int g = blockIdx.x, c = threadIdx.x;
    float invs = 1.f / (gsum[g] + 1e-16f);
    int b = goffs[g], e2 = goffs[g + 1];
    float acc = 0.f;
    for (int i = b; i < e2; ++i) acc = fmaf(es[i] * invs, bf2f(h[(size_t)i * 128 + c]), acc);
    ctx[(size_t)g * 128 + c] = acc;
}

extern "C" void kernel_launch(void* const* d_in, const int* in_sizes, int n_in,
                              void* d_out, int out_size, void* d_ws, size_t ws_size,
                              hipStream_t stream) {
    const float* x      = (const float*)d_in[0];
    const int*   ei     = (const int*)d_in[1];
    const float* ea     = (const float*)d_in[2];
    const int*   batch  = (const int*)d_in[3];
    const float* embW   = (const float*)d_in[4];
    const float* embB   = (const float*)d_in[5];
    const float* attW1  = (const float*)d_in[6];
    const float* attb1  = (const float*)d_in[7];
    const float* attW2  = (const float*)d_in[8];
    const float* attb2  = (const float*)d_in[9];
    const float* mlpW   = (const float*)d_in[10];
    const float* mlpb   = (const float*)d_in[11];
    const float* gWih   = (const float*)d_in[12];
    const float* gWhh   = (const float*)d_in[13];
    const float* gbih   = (const float*)d_in[14];
    const float* gbhh   = (const float*)d_in[15];
    const float* gattW1 = (const float*)d_in[16];
    const float* gattb1 = (const float*)d_in[17];
    const float* gattW2 = (const float*)d_in[18];
    const float* gattb2 = (const float*)d_in[19];
    const float* ggWih  = (const float*)d_in[20];
    const float* ggWhh  = (const float*)d_in[21];
    const float* ggbih  = (const float*)d_in[22];
    const float* ggbhh  = (const float*)d_in[23];
    float* out = (float*)d_out;

    void* basep = nullptr;
    (void)hipGetSymbolAddress(&basep, HIP_SYMBOL(g_afp_ws));
    char* base = (char*)basep;
    bf16*  h0b   = (bf16*)(base + OFF_H0B);
    bf16*  h1b   = (bf16*)(base + OFF_H1B);
    bf16*  xb    = (bf16*)(base + OFF_XB);
    bf16*  pqmb  = (bf16*)(base + OFF_PQMB);
    bf16*  ghx   = (bf16*)(base + OFF_GH);
    float* hW1   = (float*)(base + OFF_GI);
    bf16*  aggrb = (bf16*)(base + OFF_AGB);
    float* es    = (float*)(base + OFF_ES);
    bf16*  wt    = (bf16*)(base + OFF_WT);
    bf16*  wiht  = (bf16*)(base + OFF_WIHT);
    bf16*  embt  = (bf16*)(base + OFF_EMBT);
    float* bbig  = (float*)(base + OFF_BBIG);
    float* g0b   = (float*)(base + OFF_G0);
    float* gAb   = (float*)(base + OFF_GA);
    float* ctx   = (float*)(base + OFF_CTX);
    float* gictx = (float*)(base + OFF_GICTX);
    float* ghr   = (float*)(base + OFF_GHB);
    float* gsum  = (float*)(base + OFF_GSUM);
    int*   deg   = (int*)(base + OFF_DEG);
    int*   offs  = (int*)(base + OFF_OFFS);
    int*   cur   = (int*)(base + OFF_CUR);
    int2*  cse   = (int2*)(base + OFF_CSE);
    int*   ghist = (int*)(base + OFF_GHIST);
    int*   goffs = (int*)(base + OFF_GOFFS);
    int*   bsum  = (int*)(base + OFF_BSUM);

    (void)hipMemsetAsync(deg, 0, SZ_NF, stream);
    (void)hipMemsetAsync(cur, 0, SZ_NF, stream);
    (void)hipMemsetAsync(ghist, 0, SZ_GF, stream);
    (void)hipMemsetAsync(gsum, 0, SZ_GF, stream);

    const int nbN = (N_NODES + SCB - 1) / SCB;
    const int nbG = (N_GRAPHS + SCB - 1) / SCB;

    hist_dst_kernel<<<(N_EDGES + 255) / 256, 256, 0, stream>>>(ei, deg);
    scan_local<<<nbN, SCB, 0, stream>>>(deg, offs, bsum, N_NODES);
    scan_bsum<<<1, SCB, 0, stream>>>(bsum, nbN, offs + N_NODES);
    scan_addoff<<<nbN, SCB, 0, stream>>>(offs, bsum, N_NODES);
    scatter_cse_kernel<<<(N_EDGES + 255) / 256, 256, 0, stream>>>(ei, offs, cur, cse);
    hist_batch_kernel<<<(N_NODES + 255) / 256, 256, 0, stream>>>(batch, ghist);
    scan_local<<<nbG, SCB, 0, stream>>>(ghist, goffs, bsum, N_GRAPHS);
    scan_bsum<<<1, SCB, 0, stream>>>(bsum, nbG, goffs + N_GRAPHS);
    scan_addoff<<<nbG, SCB, 0, stream>>>(goffs, bsum, N_GRAPHS);

    cast_bf16_kernel<<<(N_NODES * FN + 255) / 256, 256, 0, stream>>>(x, xb, N_NODES * FN);
    transpose_cast<<<(FN * 128 + 255) / 256, 256, 0, stream>>>(embW, embt, FN, 128);

    {
        dim3 g((N_NODES + 63) / 64, 128 / 64);
        gemm_mfma<64><<<g, 256, 0, stream>>>(xb, embt, embB, nullptr, h0b, nullptr,
                                             N_NODES, 128, 1 | 8);
    }

    bf16* hcurb = h0b;
    bf16* hnextb = h1b;
    for (int l = 0; l < NL; ++l) {
        pack_weights_bt<<<(768 * 128 + 255) / 256, 256, 0, stream>>>(
            attW1 + (size_t)l * 272 * 128, mlpW + (size_t)l * 144 * 128,
            gWhh + (size_t)l * 128 * 384, attb1 + l * 128, mlpb + l * 128,
            gbhh + l * 384, wt, bbig);
        {
            dim3 g((N_NODES + 63) / 64, 768 / 64);
            gemm_mfma<128><<<g, 256, 0, stream>>>(hcurb, wt, bbig, nullptr, pqmb, ghx,
                                                  N_NODES, 768, 2);
        }
        edge_fused_kernel<<<(N_NODES + 3) / 4, 256, 0, stream>>>(
            pqmb, cse, ea, attW1 + (size_t)l * 272 * 128 + 256 * 128,
            attW2 + (size_t)l * 128, attb2 + l,
            mlpW + (size_t)l * 144 * 128 + 128 * 128,
            offs, aggrb);
        transpose_cast<<<(128 * 384 + 255) / 256, 256, 0, stream>>>(
            gWih + (size_t)l * 128 * 384, wiht, 128, 384);
        gemm_gru<<<(N_NODES + 63) / 64, 256, 0, stream>>>(
            aggrb, wiht, gbih + l * 384, ghx, hcurb, hnextb, N_NODES);
        bf16* tb = hcurb; hcurb = hnextb; hnextb = tb;
    }

    // readout (h fixed across T -> ctx computed once)
    graph_pool_sum<<<N_GRAPHS, 128, 0, stream>>>(hcurb, goffs, g0b);
    transpose_cast<<<(128 * 128 + 255) / 256, 256, 0, stream>>>(gattW1, wiht, 128, 128);
    {
        dim3 g((N_NODES + 63) / 64, 128 / 64);
        gemm_mfma<128><<<g, 256, 0, stream>>>(hcurb, wiht, gattb1, hW1, nullptr, nullptr,
                                              N_NODES, 128, 0);
    }
    node_score2_kernel<<<(N_NODES + 3) / 4, 256, 0, stream>>>(
        hW1, gattW2, gattb2, batch, es, gsum);
    graph_ctx_kernel<<<N_GRAPHS, 128, 0, stream>>>(hcurb, goffs, es, gsum, ctx);

    dim3 gg((N_GRAPHS + 63) / 64, 384 / 64);
    gemm_f32<<<gg, 256, 0, stream>>>(ctx, ggWih, ggbih, gictx, N_GRAPHS, H, 384);
    gemm_f32<<<gg, 256, 0, stream>>>(g0b, ggWhh, ggbhh, ghr, N_GRAPHS, H, 384);
    gru_elem_kernel<<<((size_t)N_GRAPHS * H + 255) / 256, 256, 0, stream>>>(
        gictx, ghr, g0b, gAb, N_GRAPHS);
    gemm_f32<<<gg, 256, 0, stream>>>(gAb, ggWhh, ggbhh, ghr, N_GRAPHS, H, 384);
    gru_elem_kernel<<<((size_t)N_GRAPHS * H + 255) / 256, 256, 0, stream>>>(
        gictx, ghr, gAb, out, N_GRAPHS);
}